// Round 11
// baseline (378.183 us; speedup 1.0000x reference)
//
#include <hip/hip_runtime.h>
#include <hip/hip_bf16.h>

typedef unsigned short u16;
typedef unsigned int   u32;

using f32x4  = __attribute__((ext_vector_type(4)))  float;
using f32x16 = __attribute__((ext_vector_type(16))) float;
using s16x8  = __attribute__((ext_vector_type(8)))  short;
using b16x8  = __attribute__((ext_vector_type(8)))  __bf16;
using u32x4  = __attribute__((ext_vector_type(4)))  u32;

#define LOG2E 1.44269504088896f
#define QSC   (0.03125f * LOG2E)   // SCALE * log2(e), folded into q

__device__ __forceinline__ f32x4 mfma16(s16x8 a, s16x8 b, f32x4 c) {
  return __builtin_amdgcn_mfma_f32_16x16x32_bf16(
      __builtin_bit_cast(b16x8, a), __builtin_bit_cast(b16x8, b), c, 0, 0, 0);
}
__device__ __forceinline__ f32x16 mfma32(s16x8 a, s16x8 b, f32x16 c) {
  return __builtin_amdgcn_mfma_f32_32x32x16_bf16(
      __builtin_bit_cast(b16x8, a), __builtin_bit_cast(b16x8, b), c, 0, 0, 0);
}

__device__ __forceinline__ u16 f2bf(float f) {
  u32 u = __builtin_bit_cast(u32, f);
  u = (u + 0x7FFFu + ((u >> 16) & 1u)) >> 16;
  return (u16)u;
}
__device__ __forceinline__ float exp2_hw(float x) {
  float r;
  asm("v_exp_f32 %0, %1" : "=v"(r) : "v"(x));
  return r;
}
__device__ __forceinline__ u32 cvtpk(float a, float b) {   // (lo=a, hi=b) bf16 pair, RNE
  u32 r;
  asm("v_cvt_pk_bf16_f32 %0, %1, %2" : "=v"(r) : "v"(a), "v"(b));
  return r;
}

// async global->LDS, 16B per lane; LDS dest = wave-uniform base + lane*16
__device__ __forceinline__ void gload16(const void* g, void* l) {
  __builtin_amdgcn_global_load_lds(
      (const __attribute__((address_space(1))) u32*)g,
      (__attribute__((address_space(3))) u32*)l, 16, 0, 0);
}

// ---------------- fp32 -> bf16 convert ----------------
__global__ void cvt(const float* __restrict__ in, u16* __restrict__ out, int n4) {
  int i = blockIdx.x * blockDim.x + threadIdx.x;
  int stride = gridDim.x * blockDim.x;
  for (; i < n4; i += stride) {
    float4 v = ((const float4*)in)[i];
    ushort4 o;
    o.x = f2bf(v.x); o.y = f2bf(v.y); o.z = f2bf(v.z); o.w = f2bf(v.w);
    ((ushort4*)out)[i] = o;
  }
}

// ---------------- bias rearrange into flash fragment order ----------------
// layout: flat slot s = q>>5 (64 slots of 32 queries),
// then [kt(32)][chunk(4)][lane(64)][8 vals] bf16, *LOG2E.
// vidx = chunk*8+e ; kb=vidx>>4, r=vidx&15
// true key = kt*64 + kb*32 + (r&3) + 8*(r>>2) + 4*(lane>>5)
__global__ void bias_rearrange(const float* __restrict__ ab, u16* __restrict__ out) {
  const int idx  = blockIdx.x * 256 + threadIdx.x;   // 0..524287
  const int lane = idx & 63;
  const int vo   = ((idx >> 6) & 3) * 8;             // vidx base: 0,8,16,24
  const int kt   = (idx >> 8) & 31;
  const int slot = idx >> 13;                        // 0..63 (= q>>5)
  const int hi   = lane >> 5;
  const int q    = slot * 32 + (lane & 31);
  const int kb   = vo >> 4;                 // 0 or 1
  const int so   = (vo & 8) << 1;           // +16 for r=8..15 octet
  const int kbase = kt * 64 + kb * 32 + so + 4 * hi;
  const float* src = ab + (long)q * 2048 + kbase;
  const float4 a = *(const float4*)(src);        // keys +0..3
  const float4 b = *(const float4*)(src + 8);    // keys +8..11
  u16 o[8];
  o[0] = f2bf(a.x * LOG2E); o[1] = f2bf(a.y * LOG2E);
  o[2] = f2bf(a.z * LOG2E); o[3] = f2bf(a.w * LOG2E);
  o[4] = f2bf(b.x * LOG2E); o[5] = f2bf(b.y * LOG2E);
  o[6] = f2bf(b.z * LOG2E); o[7] = f2bf(b.w * LOG2E);
  *(s16x8*)(out + (long)idx * 8) = *(s16x8*)o;
}

// ---------------- GEMM: C[M,N] = A[M,K] @ B[N,K]^T  (both bf16, row-major) ----
// 2-phase double-buffered staging (T3 minimum): stage(next) overlaps
// compute(cur); one vmcnt(0)+barrier per K-tile.
template<int EPI>
__global__ __launch_bounds__(256)
void gemm_bt(const u16* __restrict__ A, const u16* __restrict__ Bm,
             int M, int N, int K,
             const float* __restrict__ bias0, const float* __restrict__ bias1,
             u16* __restrict__ oq, u16* __restrict__ ok, u16* __restrict__ ov,
             float* __restrict__ outf)
{
  __shared__ u16 As[2][128 * 32];
  __shared__ u16 Bs[2][128 * 32];

  const int tid  = threadIdx.x;
  const int w    = tid >> 6;
  const int lane = tid & 63;
  const int lr   = lane & 15;
  const int lg   = lane >> 4;
  const int wr   = w >> 1, wc = w & 1;

  const int bm = blockIdx.y, bn = blockIdx.x;

  f32x4 acc[4][4];
#pragma unroll
  for (int i = 0; i < 4; ++i)
#pragma unroll
    for (int j = 0; j < 4; ++j) acc[i][j] = (f32x4){0.f, 0.f, 0.f, 0.f};

  const int rowA = bm * 128 + (tid >> 2);
  const int rowB = bn * 128 + (tid >> 2);
  const int colk = (tid & 3) * 8;

  const u16* ga0 = A  + (long)rowA * K + colk;
  const u16* gb0 = Bm + (long)rowB * K + colk;

  // prologue: stage tile 0
  gload16(ga0,          &As[0][w * 512]);
  gload16(ga0 + 64 * K, &As[0][2048 + w * 512]);
  gload16(gb0,          &Bs[0][w * 512]);
  gload16(gb0 + 64 * K, &Bs[0][2048 + w * 512]);
  asm volatile("s_waitcnt vmcnt(0)" ::: "memory");
  __syncthreads();

  const int NT = K >> 5;
  for (int t = 0; t < NT; ++t) {
    const int cur = t & 1;
    if (t + 1 < NT) {            // stage next tile into the other buffer
      const u16* ga = ga0 + (t + 1) * 32;
      const u16* gb = gb0 + (t + 1) * 32;
      gload16(ga,          &As[cur ^ 1][w * 512]);
      gload16(ga + 64 * K, &As[cur ^ 1][2048 + w * 512]);
      gload16(gb,          &Bs[cur ^ 1][w * 512]);
      gload16(gb + 64 * K, &Bs[cur ^ 1][2048 + w * 512]);
    }

    s16x8 af[4], bfr[4];
#pragma unroll
    for (int mi = 0; mi < 4; ++mi)
      af[mi] = *(const s16x8*)(&As[cur][(wr * 64 + mi * 16 + lr) * 32 + lg * 8]);
#pragma unroll
    for (int ni = 0; ni < 4; ++ni)
      bfr[ni] = *(const s16x8*)(&Bs[cur][(wc * 64 + ni * 16 + lr) * 32 + lg * 8]);
#pragma unroll
    for (int mi = 0; mi < 4; ++mi)
#pragma unroll
      for (int ni = 0; ni < 4; ++ni)
        acc[mi][ni] = mfma16(af[mi], bfr[ni], acc[mi][ni]);

    asm volatile("s_waitcnt vmcnt(0)" ::: "memory");   // next tile landed
    __syncthreads();                                    // all reads of cur done
  }

  const int gm0 = bm * 128 + wr * 64;
  const int gn0 = bn * 128 + wc * 64;

#pragma unroll
  for (int mi = 0; mi < 4; ++mi) {
#pragma unroll
    for (int ni = 0; ni < 4; ++ni) {
      const int col  = gn0 + ni * 16 + lr;
      const int row0 = gm0 + mi * 16 + lg * 4;
      if (EPI == 0) {
        const int which = col >> 10;          // 0=q 1=k 2=v
        const int cj    = col & 1023;
        const float badd = (which == 0) ? bias0[cj] : (which == 2 ? bias1[cj] : 0.f);
        const int h = cj >> 6, d = cj & 63;
#pragma unroll
        for (int r = 0; r < 4; ++r) {
          const int rowg = row0 + r;           // = b*2048 + l
          const int b = rowg >> 11, l = rowg & 2047;
          const int bh = b * 16 + h;
          float val = acc[mi][ni][r] + badd;
          if (which == 0) val *= QSC;          // fold softmax scale+log2e into q
          const u16 o = f2bf(val);
          if (which == 0)      oq[(bh * 2048 + l) * 64 + d] = o;
          else if (which == 1) ok[(bh * 2048 + l) * 64 + d] = o;
          else {
            // permute key bits 2<->3 so flash PV B-frags are lane-local
            const int lp = (l & ~12) | ((l & 4) << 1) | ((l & 8) >> 1);
            ov[(bh * 64 + d) * 2048 + lp] = o;
          }
        }
      } else {
        const float badd = bias0[col];
#pragma unroll
        for (int r = 0; r < 4; ++r)
          outf[(long)(row0 + r) * N + col] = acc[mi][ni][r] + badd;
      }
    }
  }
}

// ---------------- flash attention ----------------
// 1024 blocks -> (bh 0..63, qt2 0..15), XCD-swizzled (8 bh per XCD).
// 256 threads = 4 waves; wave w owns ONE 32-query fragment.  r7's proven
// per-wave datapath with qi=1: K/V/bias direct global->VGPR, fixed-max
// softmax (P = 2^s), lane-local cvt_pk P-frags, key-permuted V.
// A/B experiment: PLAIN __launch_bounds__(256) — the min-waves arg is the
// sole remaining suspect for r8/r9's small-absmax failures (2/2 fail with,
// 4/4 pass without).  2x blocks vs r10 => up to 16 waves/CU.
__global__ __launch_bounds__(256)
void flash_attn(const u16* __restrict__ qbuf, const u16* __restrict__ kbuf,
                const u16* __restrict__ vtbuf, const u16* __restrict__ biasr,
                u16* __restrict__ oup)
{
  __shared__ u32 Os[4][32][33];

  const int tid  = threadIdx.x;
  const int w    = tid >> 6;
  const int lane = tid & 63;
  const int lq   = lane & 31;
  const int hi   = lane >> 5;

  const int bid = blockIdx.x;
  const int swz = (bid & 7) * 128 + (bid >> 3);   // bijective, 1024 % 8 == 0
  const int bh  = swz >> 4, qt2 = swz & 15;
  const long base = (long)bh * (2048 * 64);

  // Q fragment (B-operand), one per wave
  const int qrow = qt2 * 128 + w * 32 + lq;
  s16x8 qf[4];
  {
    const u16* qp = qbuf + base + qrow * 64 + 8 * hi;
#pragma unroll
    for (int s = 0; s < 4; ++s) qf[s] = *(const s16x8*)(qp + 16 * s);
  }

  f32x16 oacc0, oacc1;
  float lacc[8];
#pragma unroll
  for (int r = 0; r < 16; ++r) { oacc0[r] = 0.f; oacc1[r] = 0.f; }
#pragma unroll
  for (int r = 0; r < 8; ++r) lacc[r] = 0.f;

  // bias slot = qrow>>5 = qt2*4 + w
  const u16* bslice = biasr + (long)(qt2 * 4 + w) * 65536 + lane * 8;

  for (int kt = 0; kt < 32; ++kt) {
    // K fragments (A-operand), direct global->VGPR (L2-resident tile)
    const u16* kp = kbuf + base + (kt * 64 + lq) * 64 + 8 * hi;
    s16x8 kf0[4], kf1[4];
#pragma unroll
    for (int s = 0; s < 4; ++s) {
      kf0[s] = *(const s16x8*)(kp + 16 * s);
      kf1[s] = *(const s16x8*)(kp + 2048 + 16 * s);
    }

    // V fragments (permuted key layout), direct global->VGPR
    const u16* vp = vtbuf + base + lq * 2048 + kt * 64 + 8 * hi;
    s16x8 vf0[4], vf1[4];
#pragma unroll
    for (int ks = 0; ks < 4; ++ks) {
      vf0[ks] = *(const s16x8*)(vp + 16 * ks);
      vf1[ks] = *(const s16x8*)(vp + 32 * 2048 + 16 * ks);
    }

    // bias fragments (coalesced dwordx4, bf16 pairs)
    u32x4 bb[4];
#pragma unroll
    for (int k = 0; k < 4; ++k)
      bb[k] = *(const u32x4*)(bslice + kt * 2048 + k * 512);

    // accumulator init from bias (1 VALU op per value)
    f32x16 sa0, sa1;
#pragma unroll
    for (int jw = 0; jw < 8; ++jw) {
      const u32 w0 = bb[jw >> 2][jw & 3];
      const u32 w1 = bb[2 + (jw >> 2)][jw & 3];
      sa0[2 * jw]     = __builtin_bit_cast(float, w0 << 16);
      sa0[2 * jw + 1] = __builtin_bit_cast(float, w0 & 0xFFFF0000u);
      sa1[2 * jw]     = __builtin_bit_cast(float, w1 << 16);
      sa1[2 * jw + 1] = __builtin_bit_cast(float, w1 & 0xFFFF0000u);
    }

    // S^T = K Q^T + bias  (log2 domain; q pre-scaled by QSC)
#pragma unroll
    for (int s = 0; s < 4; ++s) sa0 = mfma32(kf0[s], qf[s], sa0);
#pragma unroll
    for (int s = 0; s < 4; ++s) sa1 = mfma32(kf1[s], qf[s], sa1);

    // P = 2^s, no max subtraction; accumulate l partials
#pragma unroll
    for (int r = 0; r < 16; ++r) {
      sa0[r] = exp2_hw(sa0[r]);
      sa1[r] = exp2_hw(sa1[r]);
    }
#pragma unroll
    for (int r = 0; r < 8; ++r)
      lacc[r] += (sa0[r] + sa0[r + 8]) + (sa1[r] + sa1[r + 8]);

    // P fragments (lane-local by V key-permute)
    s16x8 pf[4];
#pragma unroll
    for (int ks = 0; ks < 4; ++ks) {
      const f32x16 ps = (ks & 2) ? sa1 : sa0;
      const int o = (ks & 1) * 8;
      u32x4 tt;
      tt[0] = cvtpk(ps[o + 0], ps[o + 1]);
      tt[1] = cvtpk(ps[o + 2], ps[o + 3]);
      tt[2] = cvtpk(ps[o + 4], ps[o + 5]);
      tt[3] = cvtpk(ps[o + 6], ps[o + 7]);
      pf[ks] = __builtin_bit_cast(s16x8, tt);
    }

    // O^T += V^T P^T
#pragma unroll
    for (int ks = 0; ks < 4; ++ks) {
      oacc0 = mfma32(vf0[ks], pf[ks], oacc0);
      oacc1 = mfma32(vf1[ks], pf[ks], oacc1);
    }
  }

  // epilogue: reduce l, normalize, transpose via LDS, store [B, L, H*D] bf16
  const int b = bh >> 4, h = bh & 15;
  float l = ((lacc[0] + lacc[1]) + (lacc[2] + lacc[3]))
          + ((lacc[4] + lacc[5]) + (lacc[6] + lacc[7]));
  l += __shfl_xor(l, 32, 64);
  const float inv = 1.f / l;
#pragma unroll
  for (int i = 0; i < 8; ++i) {
    const int idx = (i & 1) + 2 * hi + 4 * (i >> 1);   // d0 = 2*idx
    Os[w][lq][idx]      = cvtpk(oacc0[2 * i] * inv, oacc0[2 * i + 1] * inv);
    Os[w][lq][idx + 16] = cvtpk(oacc1[2 * i] * inv, oacc1[2 * i + 1] * inv);
  }
  __syncthreads();
#pragma unroll
  for (int it = 0; it < 4; ++it) {
    const int q = it * 8 + (lane >> 3);
    const int c = (lane & 7) * 4;
    u32x4 v;
#pragma unroll
    for (int j = 0; j < 4; ++j) v[j] = Os[w][q][c + j];
    const long row = (long)(b * 2048 + qt2 * 128 + w * 32 + q);
    *(u32x4*)(oup + row * 1024 + h * 64 + (lane & 7) * 8) = v;
  }
}

extern "C" void kernel_launch(void* const* d_in, const int* in_sizes, int n_in,
                              void* d_out, int out_size, void* d_ws, size_t ws_size,
                              hipStream_t stream) {
  const float* x     = (const float*)d_in[0];
  const float* ab    = (const float*)d_in[1];
  const float* wqkv  = (const float*)d_in[2];
  const float* qbias = (const float*)d_in[3];
  const float* vbias = (const float*)d_in[4];
  const float* wproj = (const float*)d_in[5];
  const float* bproj = (const float*)d_in[6];
  float* out = (float*)d_out;

  // workspace layout (80 MB total)
  char* ws = (char*)d_ws;
  if (ws_size < 83886080u) return;  // refuse to corrupt memory
  u16* xb     = (u16*)(ws);              // 16 MB; reused as oup after QKV GEMM
  u16* wqkvb  = (u16*)(ws + 16777216);   // 6 MB
  u16* wprojb = (u16*)(ws + 23068672);   // 2 MB
  u16* biasr  = (u16*)(ws + 25165824);   // 8 MB  (attn_bias, fragment order)
  u16* qbuf   = (u16*)(ws + 33554432);   // 16 MB  [B,H,L,D] (q pre-scaled)
  u16* kbuf   = (u16*)(ws + 50331648);   // 16 MB  [B,H,L,D]
  u16* vtbuf  = (u16*)(ws + 67108864);   // 16 MB  [B,H,D,L'] (key-permuted)

  cvt<<<dim3(2048), dim3(256), 0, stream>>>(x, xb, 8388608 / 4);
  cvt<<<dim3(512),  dim3(256), 0, stream>>>(wqkv, wqkvb, 3145728 / 4);
  cvt<<<dim3(256),  dim3(256), 0, stream>>>(wproj, wprojb, 1048576 / 4);
  bias_rearrange<<<dim3(2048), dim3(256), 0, stream>>>(ab, biasr);

  gemm_bt<0><<<dim3(24, 64), dim3(256), 0, stream>>>(
      xb, wqkvb, 8192, 3072, 1024, qbias, vbias, qbuf, kbuf, vtbuf, nullptr);

  flash_attn<<<dim3(1024), dim3(256), 0, stream>>>(qbuf, kbuf, vtbuf, biasr, xb);

  gemm_bt<1><<<dim3(8, 64), dim3(256), 0, stream>>>(
      xb, wprojb, 8192, 1024, 1024, bproj, nullptr, nullptr, nullptr, nullptr, out);
}

// Round 12
// 280.270 us; speedup vs baseline: 1.3494x; 1.3494x over previous
//
#include <hip/hip_runtime.h>
#include <hip/hip_bf16.h>

typedef unsigned short u16;
typedef unsigned int   u32;

using f32x4  = __attribute__((ext_vector_type(4)))  float;
using f32x16 = __attribute__((ext_vector_type(16))) float;
using s16x8  = __attribute__((ext_vector_type(8)))  short;
using b16x8  = __attribute__((ext_vector_type(8)))  __bf16;
using u32x4  = __attribute__((ext_vector_type(4)))  u32;

#define LOG2E 1.44269504088896f
#define QSC   (0.03125f * LOG2E)   // SCALE * log2(e), folded into q

__device__ __forceinline__ f32x4 mfma16(s16x8 a, s16x8 b, f32x4 c) {
  return __builtin_amdgcn_mfma_f32_16x16x32_bf16(
      __builtin_bit_cast(b16x8, a), __builtin_bit_cast(b16x8, b), c, 0, 0, 0);
}
__device__ __forceinline__ f32x16 mfma32(s16x8 a, s16x8 b, f32x16 c) {
  return __builtin_amdgcn_mfma_f32_32x32x16_bf16(
      __builtin_bit_cast(b16x8, a), __builtin_bit_cast(b16x8, b), c, 0, 0, 0);
}

__device__ __forceinline__ u16 f2bf(float f) {
  u32 u = __builtin_bit_cast(u32, f);
  u = (u + 0x7FFFu + ((u >> 16) & 1u)) >> 16;
  return (u16)u;
}
__device__ __forceinline__ float exp2_hw(float x) {
  float r;
  asm("v_exp_f32 %0, %1" : "=v"(r) : "v"(x));
  return r;
}
__device__ __forceinline__ u32 cvtpk(float a, float b) {   // (lo=a, hi=b) bf16 pair, RNE
  u32 r;
  asm("v_cvt_pk_bf16_f32 %0, %1, %2" : "=v"(r) : "v"(a), "v"(b));
  return r;
}

// async global->LDS, 16B per lane; LDS dest = wave-uniform base + lane*16
__device__ __forceinline__ void gload16(const void* g, void* l) {
  __builtin_amdgcn_global_load_lds(
      (const __attribute__((address_space(1))) u32*)g,
      (__attribute__((address_space(3))) u32*)l, 16, 0, 0);
}

// ---------------- fp32 -> bf16 convert ----------------
__global__ void cvt(const float* __restrict__ in, u16* __restrict__ out, int n4) {
  int i = blockIdx.x * blockDim.x + threadIdx.x;
  int stride = gridDim.x * blockDim.x;
  for (; i < n4; i += stride) {
    float4 v = ((const float4*)in)[i];
    ushort4 o;
    o.x = f2bf(v.x); o.y = f2bf(v.y); o.z = f2bf(v.z); o.w = f2bf(v.w);
    ((ushort4*)out)[i] = o;
  }
}

// ---------------- bias rearrange into flash fragment order ----------------
// layout: [qt(8)][w(4)][qi(2)][kt(32)][chunk(4)][lane(64)][8 vals] bf16, *LOG2E
// vidx = chunk*8+e ; kb=vidx>>4, r=vidx&15
// true key = kt*64 + kb*32 + (r&3) + 8*(r>>2) + 4*(lane>>5)
// q = qt*256 + w*64 + qi*32 + (lane&31)
__global__ void bias_rearrange(const float* __restrict__ ab, u16* __restrict__ out) {
  const int idx  = blockIdx.x * 256 + threadIdx.x;   // 0..524287
  const int lane = idx & 63;
  const int vo   = ((idx >> 6) & 3) * 8;             // vidx base: 0,8,16,24
  const int kt   = (idx >> 8) & 31;
  const int qi   = (idx >> 13) & 1;
  const int w    = (idx >> 14) & 3;
  const int qt   = (idx >> 16) & 7;
  const int hi   = lane >> 5;
  const int q    = qt * 256 + w * 64 + qi * 32 + (lane & 31);
  const int kb   = vo >> 4;                 // 0 or 1
  const int so   = (vo & 8) << 1;           // +16 for r=8..15 octet
  const int kbase = kt * 64 + kb * 32 + so + 4 * hi;
  const float* src = ab + (long)q * 2048 + kbase;
  const float4 a = *(const float4*)(src);        // keys +0..3
  const float4 b = *(const float4*)(src + 8);    // keys +8..11
  u16 o[8];
  o[0] = f2bf(a.x * LOG2E); o[1] = f2bf(a.y * LOG2E);
  o[2] = f2bf(a.z * LOG2E); o[3] = f2bf(a.w * LOG2E);
  o[4] = f2bf(b.x * LOG2E); o[5] = f2bf(b.y * LOG2E);
  o[6] = f2bf(b.z * LOG2E); o[7] = f2bf(b.w * LOG2E);
  *(s16x8*)(out + (long)idx * 8) = *(s16x8*)o;
}

// ---------------- GEMM: C[M,N] = A[M,K] @ B[N,K]^T  (both bf16, row-major) ----
// 2-phase double-buffered staging (T3 minimum): stage(next) overlaps
// compute(cur); one vmcnt(0)+barrier per K-tile.
template<int EPI>
__global__ __launch_bounds__(256)
void gemm_bt(const u16* __restrict__ A, const u16* __restrict__ Bm,
             int M, int N, int K,
             const float* __restrict__ bias0, const float* __restrict__ bias1,
             u16* __restrict__ oq, u16* __restrict__ ok, u16* __restrict__ ov,
             float* __restrict__ outf)
{
  __shared__ u16 As[2][128 * 32];
  __shared__ u16 Bs[2][128 * 32];

  const int tid  = threadIdx.x;
  const int w    = tid >> 6;
  const int lane = tid & 63;
  const int lr   = lane & 15;
  const int lg   = lane >> 4;
  const int wr   = w >> 1, wc = w & 1;

  const int bm = blockIdx.y, bn = blockIdx.x;

  f32x4 acc[4][4];
#pragma unroll
  for (int i = 0; i < 4; ++i)
#pragma unroll
    for (int j = 0; j < 4; ++j) acc[i][j] = (f32x4){0.f, 0.f, 0.f, 0.f};

  const int rowA = bm * 128 + (tid >> 2);
  const int rowB = bn * 128 + (tid >> 2);
  const int colk = (tid & 3) * 8;

  const u16* ga0 = A  + (long)rowA * K + colk;
  const u16* gb0 = Bm + (long)rowB * K + colk;

  // prologue: stage tile 0
  gload16(ga0,          &As[0][w * 512]);
  gload16(ga0 + 64 * K, &As[0][2048 + w * 512]);
  gload16(gb0,          &Bs[0][w * 512]);
  gload16(gb0 + 64 * K, &Bs[0][2048 + w * 512]);
  asm volatile("s_waitcnt vmcnt(0)" ::: "memory");
  __syncthreads();

  const int NT = K >> 5;
  for (int t = 0; t < NT; ++t) {
    const int cur = t & 1;
    if (t + 1 < NT) {            // stage next tile into the other buffer
      const u16* ga = ga0 + (t + 1) * 32;
      const u16* gb = gb0 + (t + 1) * 32;
      gload16(ga,          &As[cur ^ 1][w * 512]);
      gload16(ga + 64 * K, &As[cur ^ 1][2048 + w * 512]);
      gload16(gb,          &Bs[cur ^ 1][w * 512]);
      gload16(gb + 64 * K, &Bs[cur ^ 1][2048 + w * 512]);
    }

    s16x8 af[4], bfr[4];
#pragma unroll
    for (int mi = 0; mi < 4; ++mi)
      af[mi] = *(const s16x8*)(&As[cur][(wr * 64 + mi * 16 + lr) * 32 + lg * 8]);
#pragma unroll
    for (int ni = 0; ni < 4; ++ni)
      bfr[ni] = *(const s16x8*)(&Bs[cur][(wc * 64 + ni * 16 + lr) * 32 + lg * 8]);
#pragma unroll
    for (int mi = 0; mi < 4; ++mi)
#pragma unroll
      for (int ni = 0; ni < 4; ++ni)
        acc[mi][ni] = mfma16(af[mi], bfr[ni], acc[mi][ni]);

    asm volatile("s_waitcnt vmcnt(0)" ::: "memory");   // next tile landed
    __syncthreads();                                    // all reads of cur done
  }

  const int gm0 = bm * 128 + wr * 64;
  const int gn0 = bn * 128 + wc * 64;

#pragma unroll
  for (int mi = 0; mi < 4; ++mi) {
#pragma unroll
    for (int ni = 0; ni < 4; ++ni) {
      const int col  = gn0 + ni * 16 + lr;
      const int row0 = gm0 + mi * 16 + lg * 4;
      if (EPI == 0) {
        const int which = col >> 10;          // 0=q 1=k 2=v
        const int cj    = col & 1023;
        const float badd = (which == 0) ? bias0[cj] : (which == 2 ? bias1[cj] : 0.f);
        const int h = cj >> 6, d = cj & 63;
#pragma unroll
        for (int r = 0; r < 4; ++r) {
          const int rowg = row0 + r;           // = b*2048 + l
          const int b = rowg >> 11, l = rowg & 2047;
          const int bh = b * 16 + h;
          float val = acc[mi][ni][r] + badd;
          if (which == 0) val *= QSC;          // fold softmax scale+log2e into q
          const u16 o = f2bf(val);
          if (which == 0)      oq[(bh * 2048 + l) * 64 + d] = o;
          else if (which == 1) ok[(bh * 2048 + l) * 64 + d] = o;
          else {
            // permute key bits 2<->3 so flash PV B-frags are lane-local
            const int lp = (l & ~12) | ((l & 4) << 1) | ((l & 8) >> 1);
            ov[(bh * 64 + d) * 2048 + lp] = o;
          }
        }
      } else {
        const float badd = bias0[col];
#pragma unroll
        for (int r = 0; r < 4; ++r)
          outf[(long)(row0 + r) * N + col] = acc[mi][ni][r] + badd;
      }
    }
  }
}

// ---------------- flash attention ----------------
// r10 config (proven 153us): 512 blocks -> (qt 0..7, bh 0..63), XCD-swizzled,
// 4 waves, 64 queries/wave (qi=2), K/V/bias direct global->VGPR, fixed-max
// softmax (P = 2^s), lane-local cvt_pk P-frags, key-permuted V.
// NEW vs r10 (pure dataflow, no sync/layout changes):
//  - 2-deep register prefetch of K/V fragments: loop unrolled x2 with two
//    static fragment sets; iter kt+1's 16 loads issue before iter kt's
//    compute, hiding one L2 round-trip under MFMA+exp.  Prefetch index
//    wraps &31 (wrapped loads unused; keeps addresses in-bounds).
//  - s_setprio(1) around MFMA clusters (T5).
// NOTE: plain __launch_bounds__(256) — min-waves arg condemned (r8/r9/r11).
__global__ __launch_bounds__(256)
void flash_attn(const u16* __restrict__ qbuf, const u16* __restrict__ kbuf,
                const u16* __restrict__ vtbuf, const u16* __restrict__ biasr,
                u16* __restrict__ oup)
{
  __shared__ u32 Os[4][32][33];

  const int tid  = threadIdx.x;
  const int w    = tid >> 6;
  const int lane = tid & 63;
  const int lq   = lane & 31;
  const int hi   = lane >> 5;

  const int bid = blockIdx.x;
  const int wg  = (bid & 7) * 64 + (bid >> 3);   // bijective, 512 % 8 == 0
  const int bh  = wg >> 3, qt = wg & 7;
  const long base = (long)bh * (2048 * 64);

  // Q fragments (B-operand), 2 per wave
  s16x8 qf[2][4];
#pragma unroll
  for (int qi = 0; qi < 2; ++qi) {
    const int qrow = qt * 256 + w * 64 + qi * 32 + lq;
    const u16* qp = qbuf + base + qrow * 64 + 8 * hi;
#pragma unroll
    for (int s = 0; s < 4; ++s) qf[qi][s] = *(const s16x8*)(qp + 16 * s);
  }

  f32x16 oacc[2][2];
  float lacc[2][8];
#pragma unroll
  for (int qi = 0; qi < 2; ++qi) {
#pragma unroll
    for (int r = 0; r < 16; ++r) { oacc[qi][0][r] = 0.f; oacc[qi][1][r] = 0.f; }
#pragma unroll
    for (int r = 0; r < 8; ++r) lacc[qi][r] = 0.f;
  }

  const u16* bslice = biasr + (long)((qt * 4 + w) * 2) * 65536 + lane * 8;
  const u16* kbase_p = kbuf  + base + lq * 64 + 8 * hi;     // + kt*4096
  const u16* vbase_p = vtbuf + base + lq * 2048 + 8 * hi;   // + kt*64

  // K/V fragment sets A and B (static double-buffer)
  s16x8 kf0A[4], kf1A[4], vf0A[4], vf1A[4];
  s16x8 kf0B[4], kf1B[4], vf0B[4], vf1B[4];

#define LOADF(K0, K1, V0, V1, KT)                                   \
  {                                                                 \
    const int kt_ = (KT) & 31;                                      \
    const u16* kp_ = kbase_p + kt_ * 4096;                          \
    const u16* vp_ = vbase_p + kt_ * 64;                            \
    _Pragma("unroll")                                               \
    for (int s = 0; s < 4; ++s) {                                   \
      K0[s] = *(const s16x8*)(kp_ + 16 * s);                        \
      K1[s] = *(const s16x8*)(kp_ + 2048 + 16 * s);                 \
      V0[s] = *(const s16x8*)(vp_ + 16 * s);                        \
      V1[s] = *(const s16x8*)(vp_ + 32 * 2048 + 16 * s);            \
    }                                                               \
  }

#define COMPUTE(K0, K1, V0, V1, KT)                                              \
  {                                                                              \
    u32x4 bb[2][4];                                                              \
    _Pragma("unroll")                                                            \
    for (int qi = 0; qi < 2; ++qi)                                               \
      _Pragma("unroll")                                                          \
      for (int k = 0; k < 4; ++k)                                                \
        bb[qi][k] = *(const u32x4*)(bslice + (long)qi * 65536 + (KT) * 2048 + k * 512); \
    _Pragma("unroll")                                                            \
    for (int qi = 0; qi < 2; ++qi) {                                             \
      f32x16 sa0, sa1;                                                           \
      _Pragma("unroll")                                                          \
      for (int jw = 0; jw < 8; ++jw) {                                           \
        const u32 w0 = bb[qi][jw >> 2][jw & 3];                                  \
        const u32 w1 = bb[qi][2 + (jw >> 2)][jw & 3];                            \
        sa0[2 * jw]     = __builtin_bit_cast(float, w0 << 16);                   \
        sa0[2 * jw + 1] = __builtin_bit_cast(float, w0 & 0xFFFF0000u);           \
        sa1[2 * jw]     = __builtin_bit_cast(float, w1 << 16);                   \
        sa1[2 * jw + 1] = __builtin_bit_cast(float, w1 & 0xFFFF0000u);           \
      }                                                                          \
      __builtin_amdgcn_s_setprio(1);                                             \
      _Pragma("unroll")                                                          \
      for (int s = 0; s < 4; ++s) sa0 = mfma32(K0[s], qf[qi][s], sa0);           \
      _Pragma("unroll")                                                          \
      for (int s = 0; s < 4; ++s) sa1 = mfma32(K1[s], qf[qi][s], sa1);           \
      __builtin_amdgcn_s_setprio(0);                                             \
      _Pragma("unroll")                                                          \
      for (int r = 0; r < 16; ++r) {                                             \
        sa0[r] = exp2_hw(sa0[r]);                                                \
        sa1[r] = exp2_hw(sa1[r]);                                                \
      }                                                                          \
      _Pragma("unroll")                                                          \
      for (int r = 0; r < 8; ++r)                                                \
        lacc[qi][r] += (sa0[r] + sa0[r + 8]) + (sa1[r] + sa1[r + 8]);            \
      s16x8 pf[4];                                                               \
      _Pragma("unroll")                                                          \
      for (int ks = 0; ks < 4; ++ks) {                                           \
        const f32x16 ps = (ks & 2) ? sa1 : sa0;                                  \
        const int o = (ks & 1) * 8;                                              \
        u32x4 tt;                                                                \
        tt[0] = cvtpk(ps[o + 0], ps[o + 1]);                                     \
        tt[1] = cvtpk(ps[o + 2], ps[o + 3]);                                     \
        tt[2] = cvtpk(ps[o + 4], ps[o + 5]);                                     \
        tt[3] = cvtpk(ps[o + 6], ps[o + 7]);                                     \
        pf[ks] = __builtin_bit_cast(s16x8, tt);                                  \
      }                                                                          \
      __builtin_amdgcn_s_setprio(1);                                             \
      _Pragma("unroll")                                                          \
      for (int ks = 0; ks < 4; ++ks) {                                           \
        oacc[qi][0] = mfma32(V0[ks], pf[ks], oacc[qi][0]);                       \
        oacc[qi][1] = mfma32(V1[ks], pf[ks], oacc[qi][1]);                       \
      }                                                                          \
      __builtin_amdgcn_s_setprio(0);                                             \
    }                                                                            \
  }

  LOADF(kf0A, kf1A, vf0A, vf1A, 0);
  for (int kt = 0; kt < 32; kt += 2) {
    LOADF(kf0B, kf1B, vf0B, vf1B, kt + 1);
    COMPUTE(kf0A, kf1A, vf0A, vf1A, kt);
    LOADF(kf0A, kf1A, vf0A, vf1A, kt + 2);
    COMPUTE(kf0B, kf1B, vf0B, vf1B, kt + 1);
  }
#undef LOADF
#undef COMPUTE

  // epilogue: reduce l, normalize, transpose via LDS, store [B, L, H*D] bf16
  const int b = bh >> 4, h = bh & 15;
#pragma unroll
  for (int qi = 0; qi < 2; ++qi) {
    float l = ((lacc[qi][0] + lacc[qi][1]) + (lacc[qi][2] + lacc[qi][3]))
            + ((lacc[qi][4] + lacc[qi][5]) + (lacc[qi][6] + lacc[qi][7]));
    l += __shfl_xor(l, 32, 64);
    const float inv = 1.f / l;
#pragma unroll
    for (int i = 0; i < 8; ++i) {
      const int idx = (i & 1) + 2 * hi + 4 * (i >> 1);   // d0 = 2*idx
      Os[w][lq][idx]      = cvtpk(oacc[qi][0][2 * i] * inv, oacc[qi][0][2 * i + 1] * inv);
      Os[w][lq][idx + 16] = cvtpk(oacc[qi][1][2 * i] * inv, oacc[qi][1][2 * i + 1] * inv);
    }
    __syncthreads();
#pragma unroll
    for (int it = 0; it < 4; ++it) {
      const int q = it * 8 + (lane >> 3);
      const int c = (lane & 7) * 4;
      u32x4 v;
#pragma unroll
      for (int j = 0; j < 4; ++j) v[j] = Os[w][q][c + j];
      const long row = (long)(b * 2048 + qt * 256 + w * 64 + qi * 32 + q);
      *(u32x4*)(oup + row * 1024 + h * 64 + (lane & 7) * 8) = v;
    }
    __syncthreads();
  }
}

extern "C" void kernel_launch(void* const* d_in, const int* in_sizes, int n_in,
                              void* d_out, int out_size, void* d_ws, size_t ws_size,
                              hipStream_t stream) {
  const float* x     = (const float*)d_in[0];
  const float* ab    = (const float*)d_in[1];
  const float* wqkv  = (const float*)d_in[2];
  const float* qbias = (const float*)d_in[3];
  const float* vbias = (const float*)d_in[4];
  const float* wproj = (const float*)d_in[5];
  const float* bproj = (const float*)d_in[6];
  float* out = (float*)d_out;

  // workspace layout (80 MB total)
  char* ws = (char*)d_ws;
  if (ws_size < 83886080u) return;  // refuse to corrupt memory
  u16* xb     = (u16*)(ws);              // 16 MB; reused as oup after QKV GEMM
  u16* wqkvb  = (u16*)(ws + 16777216);   // 6 MB
  u16* wprojb = (u16*)(ws + 23068672);   // 2 MB
  u16* biasr  = (u16*)(ws + 25165824);   // 8 MB  (attn_bias, fragment order)
  u16* qbuf   = (u16*)(ws + 33554432);   // 16 MB  [B,H,L,D] (q pre-scaled)
  u16* kbuf   = (u16*)(ws + 50331648);   // 16 MB  [B,H,L,D]
  u16* vtbuf  = (u16*)(ws + 67108864);   // 16 MB  [B,H,D,L'] (key-permuted)

  cvt<<<dim3(2048), dim3(256), 0, stream>>>(x, xb, 8388608 / 4);
  cvt<<<dim3(512),  dim3(256), 0, stream>>>(wqkv, wqkvb, 3145728 / 4);
  cvt<<<dim3(256),  dim3(256), 0, stream>>>(wproj, wprojb, 1048576 / 4);
  bias_rearrange<<<dim3(2048), dim3(256), 0, stream>>>(ab, biasr);

  gemm_bt<0><<<dim3(24, 64), dim3(256), 0, stream>>>(
      xb, wqkvb, 8192, 3072, 1024, qbias, vbias, qbuf, kbuf, vtbuf, nullptr);

  flash_attn<<<dim3(512), dim3(256), 0, stream>>>(qbuf, kbuf, vtbuf, biasr, xb);

  gemm_bt<1><<<dim3(8, 64), dim3(256), 0, stream>>>(
      xb, wprojb, 8192, 1024, 1024, bproj, nullptr, nullptr, nullptr, nullptr, out);
}

// Round 13
// 253.643 us; speedup vs baseline: 1.4910x; 1.1050x over previous
//
#include <hip/hip_runtime.h>
#include <hip/hip_bf16.h>

typedef unsigned short u16;
typedef unsigned int   u32;

using f32x4  = __attribute__((ext_vector_type(4)))  float;
using f32x16 = __attribute__((ext_vector_type(16))) float;
using s16x8  = __attribute__((ext_vector_type(8)))  short;
using b16x8  = __attribute__((ext_vector_type(8)))  __bf16;
using u32x4  = __attribute__((ext_vector_type(4)))  u32;

#define LOG2E 1.44269504088896f
#define QSC   (0.03125f * LOG2E)   // SCALE * log2(e), folded into q

__device__ __forceinline__ f32x4 mfma16(s16x8 a, s16x8 b, f32x4 c) {
  return __builtin_amdgcn_mfma_f32_16x16x32_bf16(
      __builtin_bit_cast(b16x8, a), __builtin_bit_cast(b16x8, b), c, 0, 0, 0);
}
__device__ __forceinline__ f32x16 mfma32(s16x8 a, s16x8 b, f32x16 c) {
  return __builtin_amdgcn_mfma_f32_32x32x16_bf16(
      __builtin_bit_cast(b16x8, a), __builtin_bit_cast(b16x8, b), c, 0, 0, 0);
}

__device__ __forceinline__ u16 f2bf(float f) {
  u32 u = __builtin_bit_cast(u32, f);
  u = (u + 0x7FFFu + ((u >> 16) & 1u)) >> 16;
  return (u16)u;
}
__device__ __forceinline__ float exp2_hw(float x) {
  float r;
  asm("v_exp_f32 %0, %1" : "=v"(r) : "v"(x));
  return r;
}
__device__ __forceinline__ u32 cvtpk(float a, float b) {   // (lo=a, hi=b) bf16 pair, RNE
  u32 r;
  asm("v_cvt_pk_bf16_f32 %0, %1, %2" : "=v"(r) : "v"(a), "v"(b));
  return r;
}

// async global->LDS, 16B per lane; LDS dest = wave-uniform base + lane*16
__device__ __forceinline__ void gload16(const void* g, void* l) {
  __builtin_amdgcn_global_load_lds(
      (const __attribute__((address_space(1))) u32*)g,
      (__attribute__((address_space(3))) u32*)l, 16, 0, 0);
}

// ---------------- fp32 -> bf16 convert ----------------
__global__ void cvt(const float* __restrict__ in, u16* __restrict__ out, int n4) {
  int i = blockIdx.x * blockDim.x + threadIdx.x;
  int stride = gridDim.x * blockDim.x;
  for (; i < n4; i += stride) {
    float4 v = ((const float4*)in)[i];
    ushort4 o;
    o.x = f2bf(v.x); o.y = f2bf(v.y); o.z = f2bf(v.z); o.w = f2bf(v.w);
    ((ushort4*)out)[i] = o;
  }
}

// ---------------- bias rearrange into flash fragment order ----------------
// layout: [qt(8)][w(4)][qi(2)][kt(32)][chunk(4)][lane(64)][8 vals] bf16, *LOG2E
// vidx = chunk*8+e ; kb=vidx>>4, r=vidx&15
// true key = kt*64 + kb*32 + (r&3) + 8*(r>>2) + 4*(lane>>5)
// q = qt*256 + w*64 + qi*32 + (lane&31)
__global__ void bias_rearrange(const float* __restrict__ ab, u16* __restrict__ out) {
  const int idx  = blockIdx.x * 256 + threadIdx.x;   // 0..524287
  const int lane = idx & 63;
  const int vo   = ((idx >> 6) & 3) * 8;             // vidx base: 0,8,16,24
  const int kt   = (idx >> 8) & 31;
  const int qi   = (idx >> 13) & 1;
  const int w    = (idx >> 14) & 3;
  const int qt   = (idx >> 16) & 7;
  const int hi   = lane >> 5;
  const int q    = qt * 256 + w * 64 + qi * 32 + (lane & 31);
  const int kb   = vo >> 4;                 // 0 or 1
  const int so   = (vo & 8) << 1;           // +16 for r=8..15 octet
  const int kbase = kt * 64 + kb * 32 + so + 4 * hi;
  const float* src = ab + (long)q * 2048 + kbase;
  const float4 a = *(const float4*)(src);        // keys +0..3
  const float4 b = *(const float4*)(src + 8);    // keys +8..11
  u16 o[8];
  o[0] = f2bf(a.x * LOG2E); o[1] = f2bf(a.y * LOG2E);
  o[2] = f2bf(a.z * LOG2E); o[3] = f2bf(a.w * LOG2E);
  o[4] = f2bf(b.x * LOG2E); o[5] = f2bf(b.y * LOG2E);
  o[6] = f2bf(b.z * LOG2E); o[7] = f2bf(b.w * LOG2E);
  *(s16x8*)(out + (long)idx * 8) = *(s16x8*)o;
}

// ---------------- GEMM: C[M,N] = A[M,K] @ B[N,K]^T  (both bf16, row-major) ----
// 2-phase double-buffered staging (T3 minimum): stage(next) overlaps
// compute(cur); one vmcnt(0)+barrier per K-tile.
template<int EPI>
__global__ __launch_bounds__(256)
void gemm_bt(const u16* __restrict__ A, const u16* __restrict__ Bm,
             int M, int N, int K,
             const float* __restrict__ bias0, const float* __restrict__ bias1,
             u16* __restrict__ oq, u16* __restrict__ ok, u16* __restrict__ ov,
             float* __restrict__ outf)
{
  __shared__ u16 As[2][128 * 32];
  __shared__ u16 Bs[2][128 * 32];

  const int tid  = threadIdx.x;
  const int w    = tid >> 6;
  const int lane = tid & 63;
  const int lr   = lane & 15;
  const int lg   = lane >> 4;
  const int wr   = w >> 1, wc = w & 1;

  const int bm = blockIdx.y, bn = blockIdx.x;

  f32x4 acc[4][4];
#pragma unroll
  for (int i = 0; i < 4; ++i)
#pragma unroll
    for (int j = 0; j < 4; ++j) acc[i][j] = (f32x4){0.f, 0.f, 0.f, 0.f};

  const int rowA = bm * 128 + (tid >> 2);
  const int rowB = bn * 128 + (tid >> 2);
  const int colk = (tid & 3) * 8;

  const u16* ga0 = A  + (long)rowA * K + colk;
  const u16* gb0 = Bm + (long)rowB * K + colk;

  // prologue: stage tile 0
  gload16(ga0,          &As[0][w * 512]);
  gload16(ga0 + 64 * K, &As[0][2048 + w * 512]);
  gload16(gb0,          &Bs[0][w * 512]);
  gload16(gb0 + 64 * K, &Bs[0][2048 + w * 512]);
  asm volatile("s_waitcnt vmcnt(0)" ::: "memory");
  __syncthreads();

  const int NT = K >> 5;
  for (int t = 0; t < NT; ++t) {
    const int cur = t & 1;
    if (t + 1 < NT) {            // stage next tile into the other buffer
      const u16* ga = ga0 + (t + 1) * 32;
      const u16* gb = gb0 + (t + 1) * 32;
      gload16(ga,          &As[cur ^ 1][w * 512]);
      gload16(ga + 64 * K, &As[cur ^ 1][2048 + w * 512]);
      gload16(gb,          &Bs[cur ^ 1][w * 512]);
      gload16(gb + 64 * K, &Bs[cur ^ 1][2048 + w * 512]);
    }

    s16x8 af[4], bfr[4];
#pragma unroll
    for (int mi = 0; mi < 4; ++mi)
      af[mi] = *(const s16x8*)(&As[cur][(wr * 64 + mi * 16 + lr) * 32 + lg * 8]);
#pragma unroll
    for (int ni = 0; ni < 4; ++ni)
      bfr[ni] = *(const s16x8*)(&Bs[cur][(wc * 64 + ni * 16 + lr) * 32 + lg * 8]);
#pragma unroll
    for (int mi = 0; mi < 4; ++mi)
#pragma unroll
      for (int ni = 0; ni < 4; ++ni)
        acc[mi][ni] = mfma16(af[mi], bfr[ni], acc[mi][ni]);

    asm volatile("s_waitcnt vmcnt(0)" ::: "memory");   // next tile landed
    __syncthreads();                                    // all reads of cur done
  }

  const int gm0 = bm * 128 + wr * 64;
  const int gn0 = bn * 128 + wc * 64;

#pragma unroll
  for (int mi = 0; mi < 4; ++mi) {
#pragma unroll
    for (int ni = 0; ni < 4; ++ni) {
      const int col  = gn0 + ni * 16 + lr;
      const int row0 = gm0 + mi * 16 + lg * 4;
      if (EPI == 0) {
        const int which = col >> 10;          // 0=q 1=k 2=v
        const int cj    = col & 1023;
        const float badd = (which == 0) ? bias0[cj] : (which == 2 ? bias1[cj] : 0.f);
        const int h = cj >> 6, d = cj & 63;
#pragma unroll
        for (int r = 0; r < 4; ++r) {
          const int rowg = row0 + r;           // = b*2048 + l
          const int b = rowg >> 11, l = rowg & 2047;
          const int bh = b * 16 + h;
          float val = acc[mi][ni][r] + badd;
          if (which == 0) val *= QSC;          // fold softmax scale+log2e into q
          const u16 o = f2bf(val);
          if (which == 0)      oq[(bh * 2048 + l) * 64 + d] = o;
          else if (which == 1) ok[(bh * 2048 + l) * 64 + d] = o;
          else {
            // permute key bits 2<->3 so flash PV B-frags are lane-local
            const int lp = (l & ~12) | ((l & 4) << 1) | ((l & 8) >> 1);
            ov[(bh * 64 + d) * 2048 + lp] = o;
          }
        }
      } else {
        const float badd = bias0[col];
#pragma unroll
        for (int r = 0; r < 4; ++r)
          outf[(long)(row0 + r) * N + col] = acc[mi][ni][r] + badd;
      }
    }
  }
}

// ---------------- flash attention ----------------
// r10 config (512 blocks -> (qt,bh) XCD-swizzled, 4 waves, 64 queries/wave,
// fixed-max softmax, lane-local cvt_pk P-frags, key-permuted V) with the K/V
// fragment gathers replaced by COALESCED reg-staged LDS tiles:
//  - global loads: thread tid reads row tid>>3, 16B chunk tid&7 -> 8 full
//    contiguous 128B rows per wave-inst (vs 32 scattered lines of the direct
//    gather: the r10 counters showed 10K cyc/iter = transaction-bound).
//  - LDS tile padded to 72 elems/row (144B): row stride rotates banks by 4,
//    so fragment ds_reads are bank-balanced with NO xor swizzle.
//  - classic 1-barrier/iter double buffer: load(kt+1)->regs early, compute
//    from buf[cur], ds_write regs->buf[cur^1] late (T14), barrier.
// NOTE: plain __launch_bounds__(256) — min-waves arg condemned (r8/r9/r11).
__global__ __launch_bounds__(256)
void flash_attn(const u16* __restrict__ qbuf, const u16* __restrict__ kbuf,
                const u16* __restrict__ vtbuf, const u16* __restrict__ biasr,
                u16* __restrict__ oup)
{
  __shared__ u16 Ks[2][64 * 72];
  __shared__ u16 Vs[2][64 * 72];
  __shared__ u32 Os[4][32][33];

  const int tid  = threadIdx.x;
  const int w    = tid >> 6;
  const int lane = tid & 63;
  const int lq   = lane & 31;
  const int hi   = lane >> 5;

  const int bid = blockIdx.x;
  const int wg  = (bid & 7) * 64 + (bid >> 3);   // bijective, 512 % 8 == 0
  const int bh  = wg >> 3, qt = wg & 7;
  const long base = (long)bh * (2048 * 64);

  // Q fragments (B-operand), 2 per wave
  s16x8 qf[2][4];
#pragma unroll
  for (int qi = 0; qi < 2; ++qi) {
    const int qrow = qt * 256 + w * 64 + qi * 32 + lq;
    const u16* qp = qbuf + base + qrow * 64 + 8 * hi;
#pragma unroll
    for (int s = 0; s < 4; ++s) qf[qi][s] = *(const s16x8*)(qp + 16 * s);
  }

  f32x16 oacc[2][2];
  float lacc[2][8];
#pragma unroll
  for (int qi = 0; qi < 2; ++qi) {
#pragma unroll
    for (int r = 0; r < 16; ++r) { oacc[qi][0][r] = 0.f; oacc[qi][1][r] = 0.f; }
#pragma unroll
    for (int r = 0; r < 8; ++r) lacc[qi][r] = 0.f;
  }

  const u16* bslice = biasr + (long)((qt * 4 + w) * 2) * 65536 + lane * 8;

  // staging geometry: row sr in [0,32), chunk scc in [0,8)
  const int sr  = tid >> 3;
  const int scc = tid & 7;
  const u16* kg = kbuf  + base + sr * 64   + scc * 8;   // + kt*4096 ; +2048 = rows 32..63
  const u16* vg = vtbuf + base + sr * 2048 + scc * 8;   // + kt*64   ; +65536 = d 32..63
  const int wo0 = sr * 72 + scc * 8;
  const int wo1 = (32 + sr) * 72 + scc * 8;

  // prologue: stage tile 0
  {
    const s16x8 a0 = *(const s16x8*)(kg);
    const s16x8 a1 = *(const s16x8*)(kg + 2048);
    const s16x8 b0 = *(const s16x8*)(vg);
    const s16x8 b1 = *(const s16x8*)(vg + 65536);
    *(s16x8*)(&Ks[0][wo0]) = a0;  *(s16x8*)(&Ks[0][wo1]) = a1;
    *(s16x8*)(&Vs[0][wo0]) = b0;  *(s16x8*)(&Vs[0][wo1]) = b1;
  }
  __syncthreads();

  for (int kt = 0; kt < 32; ++kt) {
    const int cur = kt & 1;

    // issue next tile's global loads early (land under this iter's compute)
    s16x8 nk0, nk1, nv0, nv1;
    if (kt < 31) {
      const u16* kn = kg + (kt + 1) * 4096;
      const u16* vn = vg + (kt + 1) * 64;
      nk0 = *(const s16x8*)(kn);
      nk1 = *(const s16x8*)(kn + 2048);
      nv0 = *(const s16x8*)(vn);
      nv1 = *(const s16x8*)(vn + 65536);
    }

    // K/V fragments from LDS (padded rows; bank-balanced)
    s16x8 kf0[4], kf1[4], vf0[4], vf1[4];
    {
      const u16* kb0 = &Ks[cur][lq * 72];
      const u16* kb1 = &Ks[cur][(32 + lq) * 72];
      const u16* vb0 = &Vs[cur][lq * 72];
      const u16* vb1 = &Vs[cur][(32 + lq) * 72];
#pragma unroll
      for (int s = 0; s < 4; ++s) {
        const int off = (2 * s + hi) * 8;
        kf0[s] = *(const s16x8*)(kb0 + off);
        kf1[s] = *(const s16x8*)(kb1 + off);
        vf0[s] = *(const s16x8*)(vb0 + off);
        vf1[s] = *(const s16x8*)(vb1 + off);
      }
    }

    // bias fragments (coalesced dwordx4, bf16 pairs)
    u32x4 bb[2][4];
#pragma unroll
    for (int qi = 0; qi < 2; ++qi)
#pragma unroll
      for (int k = 0; k < 4; ++k)
        bb[qi][k] = *(const u32x4*)(bslice + (long)qi * 65536 + kt * 2048 + k * 512);

#pragma unroll
    for (int qi = 0; qi < 2; ++qi) {
      // accumulator init from bias (1 VALU op per value)
      f32x16 sa0, sa1;
#pragma unroll
      for (int jw = 0; jw < 8; ++jw) {
        const u32 w0 = bb[qi][jw >> 2][jw & 3];
        const u32 w1 = bb[qi][2 + (jw >> 2)][jw & 3];
        sa0[2 * jw]     = __builtin_bit_cast(float, w0 << 16);
        sa0[2 * jw + 1] = __builtin_bit_cast(float, w0 & 0xFFFF0000u);
        sa1[2 * jw]     = __builtin_bit_cast(float, w1 << 16);
        sa1[2 * jw + 1] = __builtin_bit_cast(float, w1 & 0xFFFF0000u);
      }

      // S^T = K Q^T + bias  (log2 domain; q pre-scaled by QSC)
#pragma unroll
      for (int s = 0; s < 4; ++s) sa0 = mfma32(kf0[s], qf[qi][s], sa0);
#pragma unroll
      for (int s = 0; s < 4; ++s) sa1 = mfma32(kf1[s], qf[qi][s], sa1);

      // P = 2^s, no max subtraction; accumulate l partials
#pragma unroll
      for (int r = 0; r < 16; ++r) {
        sa0[r] = exp2_hw(sa0[r]);
        sa1[r] = exp2_hw(sa1[r]);
      }
#pragma unroll
      for (int r = 0; r < 8; ++r)
        lacc[qi][r] += (sa0[r] + sa0[r + 8]) + (sa1[r] + sa1[r + 8]);

      // P fragments (lane-local by V key-permute)
      s16x8 pf[4];
#pragma unroll
      for (int ks = 0; ks < 4; ++ks) {
        const f32x16 ps = (ks & 2) ? sa1 : sa0;
        const int o = (ks & 1) * 8;
        u32x4 tt;
        tt[0] = cvtpk(ps[o + 0], ps[o + 1]);
        tt[1] = cvtpk(ps[o + 2], ps[o + 3]);
        tt[2] = cvtpk(ps[o + 4], ps[o + 5]);
        tt[3] = cvtpk(ps[o + 6], ps[o + 7]);
        pf[ks] = __builtin_bit_cast(s16x8, tt);
      }

      // O^T += V^T P^T
#pragma unroll
      for (int ks = 0; ks < 4; ++ks) {
        oacc[qi][0] = mfma32(vf0[ks], pf[ks], oacc[qi][0]);
        oacc[qi][1] = mfma32(vf1[ks], pf[ks], oacc[qi][1]);
      }
    }

    // write next tile into the other buffer (its readers wait at the barrier)
    if (kt < 31) {
      *(s16x8*)(&Ks[cur ^ 1][wo0]) = nk0;
      *(s16x8*)(&Ks[cur ^ 1][wo1]) = nk1;
      *(s16x8*)(&Vs[cur ^ 1][wo0]) = nv0;
      *(s16x8*)(&Vs[cur ^ 1][wo1]) = nv1;
    }
    __syncthreads();
  }

  // epilogue: reduce l, normalize, transpose via LDS, store [B, L, H*D] bf16
  const int b = bh >> 4, h = bh & 15;
#pragma unroll
  for (int qi = 0; qi < 2; ++qi) {
    float l = ((lacc[qi][0] + lacc[qi][1]) + (lacc[qi][2] + lacc[qi][3]))
            + ((lacc[qi][4] + lacc[qi][5]) + (lacc[qi][6] + lacc[qi][7]));
    l += __shfl_xor(l, 32, 64);
    const float inv = 1.f / l;
#pragma unroll
    for (int i = 0; i < 8; ++i) {
      const int idx = (i & 1) + 2 * hi + 4 * (i >> 1);   // d0 = 2*idx
      Os[w][lq][idx]      = cvtpk(oacc[qi][0][2 * i] * inv, oacc[qi][0][2 * i + 1] * inv);
      Os[w][lq][idx + 16] = cvtpk(oacc[qi][1][2 * i] * inv, oacc[qi][1][2 * i + 1] * inv);
    }
    __syncthreads();
#pragma unroll
    for (int it = 0; it < 4; ++it) {
      const int q = it * 8 + (lane >> 3);
      const int c = (lane & 7) * 4;
      u32x4 v;
#pragma unroll
      for (int j = 0; j < 4; ++j) v[j] = Os[w][q][c + j];
      const long row = (long)(b * 2048 + qt * 256 + w * 64 + qi * 32 + q);
      *(u32x4*)(oup + row * 1024 + h * 64 + (lane & 7) * 8) = v;
    }
    __syncthreads();
  }
}

extern "C" void kernel_launch(void* const* d_in, const int* in_sizes, int n_in,
                              void* d_out, int out_size, void* d_ws, size_t ws_size,
                              hipStream_t stream) {
  const float* x     = (const float*)d_in[0];
  const float* ab    = (const float*)d_in[1];
  const float* wqkv  = (const float*)d_in[2];
  const float* qbias = (const float*)d_in[3];
  const float* vbias = (const float*)d_in[4];
  const float* wproj = (const float*)d_in[5];
  const float* bproj = (const float*)d_in[6];
  float* out = (float*)d_out;

  // workspace layout (80 MB total)
  char* ws = (char*)d_ws;
  if (ws_size < 83886080u) return;  // refuse to corrupt memory
  u16* xb     = (u16*)(ws);              // 16 MB; reused as oup after QKV GEMM
  u16* wqkvb  = (u16*)(ws + 16777216);   // 6 MB
  u16* wprojb = (u16*)(ws + 23068672);   // 2 MB
  u16* biasr  = (u16*)(ws + 25165824);   // 8 MB  (attn_bias, fragment order)
  u16* qbuf   = (u16*)(ws + 33554432);   // 16 MB  [B,H,L,D] (q pre-scaled)
  u16* kbuf   = (u16*)(ws + 50331648);   // 16 MB  [B,H,L,D]
  u16* vtbuf  = (u16*)(ws + 67108864);   // 16 MB  [B,H,D,L'] (key-permuted)

  cvt<<<dim3(2048), dim3(256), 0, stream>>>(x, xb, 8388608 / 4);
  cvt<<<dim3(512),  dim3(256), 0, stream>>>(wqkv, wqkvb, 3145728 / 4);
  cvt<<<dim3(256),  dim3(256), 0, stream>>>(wproj, wprojb, 1048576 / 4);
  bias_rearrange<<<dim3(2048), dim3(256), 0, stream>>>(ab, biasr);

  gemm_bt<0><<<dim3(24, 64), dim3(256), 0, stream>>>(
      xb, wqkvb, 8192, 3072, 1024, qbias, vbias, qbuf, kbuf, vtbuf, nullptr);

  flash_attn<<<dim3(512), dim3(256), 0, stream>>>(qbuf, kbuf, vtbuf, biasr, xb);

  gemm_bt<1><<<dim3(8, 64), dim3(256), 0, stream>>>(
      xb, wprojb, 8192, 1024, 1024, bproj, nullptr, nullptr, nullptr, nullptr, out);
}

// Round 14
// 249.130 us; speedup vs baseline: 1.5180x; 1.0181x over previous
//
#include <hip/hip_runtime.h>
#include <hip/hip_bf16.h>

typedef unsigned short u16;
typedef unsigned int   u32;

using f32x4  = __attribute__((ext_vector_type(4)))  float;
using f32x16 = __attribute__((ext_vector_type(16))) float;
using s16x8  = __attribute__((ext_vector_type(8)))  short;
using b16x8  = __attribute__((ext_vector_type(8)))  __bf16;
using u32x4  = __attribute__((ext_vector_type(4)))  u32;

#define LOG2E 1.44269504088896f
#define QSC   (0.03125f * LOG2E)   // SCALE * log2(e), folded into q

__device__ __forceinline__ f32x4 mfma16(s16x8 a, s16x8 b, f32x4 c) {
  return __builtin_amdgcn_mfma_f32_16x16x32_bf16(
      __builtin_bit_cast(b16x8, a), __builtin_bit_cast(b16x8, b), c, 0, 0, 0);
}
__device__ __forceinline__ f32x16 mfma32(s16x8 a, s16x8 b, f32x16 c) {
  return __builtin_amdgcn_mfma_f32_32x32x16_bf16(
      __builtin_bit_cast(b16x8, a), __builtin_bit_cast(b16x8, b), c, 0, 0, 0);
}

__device__ __forceinline__ u16 f2bf(float f) {
  u32 u = __builtin_bit_cast(u32, f);
  u = (u + 0x7FFFu + ((u >> 16) & 1u)) >> 16;
  return (u16)u;
}
__device__ __forceinline__ float exp2_hw(float x) {
  float r;
  asm("v_exp_f32 %0, %1" : "=v"(r) : "v"(x));
  return r;
}
__device__ __forceinline__ u32 cvtpk(float a, float b) {   // (lo=a, hi=b) bf16 pair, RNE
  u32 r;
  asm("v_cvt_pk_bf16_f32 %0, %1, %2" : "=v"(r) : "v"(a), "v"(b));
  return r;
}

// async global->LDS, 16B per lane; LDS dest = wave-uniform base + lane*16
__device__ __forceinline__ void gload16(const void* g, void* l) {
  __builtin_amdgcn_global_load_lds(
      (const __attribute__((address_space(1))) u32*)g,
      (__attribute__((address_space(3))) u32*)l, 16, 0, 0);
}

// ---------------- fp32 -> bf16 convert ----------------
__global__ void cvt(const float* __restrict__ in, u16* __restrict__ out, int n4) {
  int i = blockIdx.x * blockDim.x + threadIdx.x;
  int stride = gridDim.x * blockDim.x;
  for (; i < n4; i += stride) {
    float4 v = ((const float4*)in)[i];
    ushort4 o;
    o.x = f2bf(v.x); o.y = f2bf(v.y); o.z = f2bf(v.z); o.w = f2bf(v.w);
    ((ushort4*)out)[i] = o;
  }
}

// ---------------- bias rearrange into flash fragment order ----------------
// layout: [qt(8)][w(4)][qi(2)][kt(32)][chunk(4)][lane(64)][8 vals] bf16, *LOG2E
// vidx = chunk*8+e ; kb=vidx>>4, r=vidx&15
// true key = kt*64 + kb*32 + (r&3) + 8*(r>>2) + 4*(lane>>5)
// q = qt*256 + w*64 + qi*32 + (lane&31)
__global__ void bias_rearrange(const float* __restrict__ ab, u16* __restrict__ out) {
  const int idx  = blockIdx.x * 256 + threadIdx.x;   // 0..524287
  const int lane = idx & 63;
  const int vo   = ((idx >> 6) & 3) * 8;             // vidx base: 0,8,16,24
  const int kt   = (idx >> 8) & 31;
  const int qi   = (idx >> 13) & 1;
  const int w    = (idx >> 14) & 3;
  const int qt   = (idx >> 16) & 7;
  const int hi   = lane >> 5;
  const int q    = qt * 256 + w * 64 + qi * 32 + (lane & 31);
  const int kb   = vo >> 4;                 // 0 or 1
  const int so   = (vo & 8) << 1;           // +16 for r=8..15 octet
  const int kbase = kt * 64 + kb * 32 + so + 4 * hi;
  const float* src = ab + (long)q * 2048 + kbase;
  const float4 a = *(const float4*)(src);        // keys +0..3
  const float4 b = *(const float4*)(src + 8);    // keys +8..11
  u16 o[8];
  o[0] = f2bf(a.x * LOG2E); o[1] = f2bf(a.y * LOG2E);
  o[2] = f2bf(a.z * LOG2E); o[3] = f2bf(a.w * LOG2E);
  o[4] = f2bf(b.x * LOG2E); o[5] = f2bf(b.y * LOG2E);
  o[6] = f2bf(b.z * LOG2E); o[7] = f2bf(b.w * LOG2E);
  *(s16x8*)(out + (long)idx * 8) = *(s16x8*)o;
}

// ---------------- GEMM: C[M,N] = A[M,K] @ B[N,K]^T  (both bf16, row-major) ----
// 2-phase double-buffered staging (T3 minimum): stage(next) overlaps
// compute(cur); one vmcnt(0)+barrier per K-tile.
template<int EPI>
__global__ __launch_bounds__(256)
void gemm_bt(const u16* __restrict__ A, const u16* __restrict__ Bm,
             int M, int N, int K,
             const float* __restrict__ bias0, const float* __restrict__ bias1,
             u16* __restrict__ oq, u16* __restrict__ ok, u16* __restrict__ ov,
             float* __restrict__ outf)
{
  __shared__ u16 As[2][128 * 32];
  __shared__ u16 Bs[2][128 * 32];

  const int tid  = threadIdx.x;
  const int w    = tid >> 6;
  const int lane = tid & 63;
  const int lr   = lane & 15;
  const int lg   = lane >> 4;
  const int wr   = w >> 1, wc = w & 1;

  const int bm = blockIdx.y, bn = blockIdx.x;

  f32x4 acc[4][4];
#pragma unroll
  for (int i = 0; i < 4; ++i)
#pragma unroll
    for (int j = 0; j < 4; ++j) acc[i][j] = (f32x4){0.f, 0.f, 0.f, 0.f};

  const int rowA = bm * 128 + (tid >> 2);
  const int rowB = bn * 128 + (tid >> 2);
  const int colk = (tid & 3) * 8;

  const u16* ga0 = A  + (long)rowA * K + colk;
  const u16* gb0 = Bm + (long)rowB * K + colk;

  // prologue: stage tile 0
  gload16(ga0,          &As[0][w * 512]);
  gload16(ga0 + 64 * K, &As[0][2048 + w * 512]);
  gload16(gb0,          &Bs[0][w * 512]);
  gload16(gb0 + 64 * K, &Bs[0][2048 + w * 512]);
  asm volatile("s_waitcnt vmcnt(0)" ::: "memory");
  __syncthreads();

  const int NT = K >> 5;
  for (int t = 0; t < NT; ++t) {
    const int cur = t & 1;
    if (t + 1 < NT) {            // stage next tile into the other buffer
      const u16* ga = ga0 + (t + 1) * 32;
      const u16* gb = gb0 + (t + 1) * 32;
      gload16(ga,          &As[cur ^ 1][w * 512]);
      gload16(ga + 64 * K, &As[cur ^ 1][2048 + w * 512]);
      gload16(gb,          &Bs[cur ^ 1][w * 512]);
      gload16(gb + 64 * K, &Bs[cur ^ 1][2048 + w * 512]);
    }

    s16x8 af[4], bfr[4];
#pragma unroll
    for (int mi = 0; mi < 4; ++mi)
      af[mi] = *(const s16x8*)(&As[cur][(wr * 64 + mi * 16 + lr) * 32 + lg * 8]);
#pragma unroll
    for (int ni = 0; ni < 4; ++ni)
      bfr[ni] = *(const s16x8*)(&Bs[cur][(wc * 64 + ni * 16 + lr) * 32 + lg * 8]);
#pragma unroll
    for (int mi = 0; mi < 4; ++mi)
#pragma unroll
      for (int ni = 0; ni < 4; ++ni)
        acc[mi][ni] = mfma16(af[mi], bfr[ni], acc[mi][ni]);

    asm volatile("s_waitcnt vmcnt(0)" ::: "memory");   // next tile landed
    __syncthreads();                                    // all reads of cur done
  }

  const int gm0 = bm * 128 + wr * 64;
  const int gn0 = bn * 128 + wc * 64;

#pragma unroll
  for (int mi = 0; mi < 4; ++mi) {
#pragma unroll
    for (int ni = 0; ni < 4; ++ni) {
      const int col  = gn0 + ni * 16 + lr;
      const int row0 = gm0 + mi * 16 + lg * 4;
      if (EPI == 0) {
        const int which = col >> 10;          // 0=q 1=k 2=v
        const int cj    = col & 1023;
        const float badd = (which == 0) ? bias0[cj] : (which == 2 ? bias1[cj] : 0.f);
        const int h = cj >> 6, d = cj & 63;
#pragma unroll
        for (int r = 0; r < 4; ++r) {
          const int rowg = row0 + r;           // = b*2048 + l
          const int b = rowg >> 11, l = rowg & 2047;
          const int bh = b * 16 + h;
          float val = acc[mi][ni][r] + badd;
          if (which == 0) val *= QSC;          // fold softmax scale+log2e into q
          const u16 o = f2bf(val);
          if (which == 0)      oq[(bh * 2048 + l) * 64 + d] = o;
          else if (which == 1) ok[(bh * 2048 + l) * 64 + d] = o;
          else {
            // permute key bits 2<->3 so flash PV B-frags are lane-local
            const int lp = (l & ~12) | ((l & 4) << 1) | ((l & 8) >> 1);
            ov[(bh * 64 + d) * 2048 + lp] = o;
          }
        }
      } else {
        const float badd = bias0[col];
#pragma unroll
        for (int r = 0; r < 4; ++r)
          outf[(long)(row0 + r) * N + col] = acc[mi][ni][r] + badd;
      }
    }
  }
}

// ---------------- flash attention ----------------
// r13 structure (512 blocks -> (qt,bh) XCD-swizzled, 4 waves, 64 queries/wave,
// coalesced reg-staged LDS K/V tiles with padded rows, fixed-max softmax,
// lane-local cvt_pk P-frags, key-permuted V) + NEW: bias fragments
// double-buffered in registers (bbA/bbB, loop unrolled x2, static indices) —
// bias(kt+1) loads issue with K/V(kt+1) and land under iter kt's compute,
// removing the last in-iteration global-latency item from the critical path.
// NOTE: plain __launch_bounds__(256) — min-waves arg condemned (r8/r9/r11).
__global__ __launch_bounds__(256)
void flash_attn(const u16* __restrict__ qbuf, const u16* __restrict__ kbuf,
                const u16* __restrict__ vtbuf, const u16* __restrict__ biasr,
                u16* __restrict__ oup)
{
  __shared__ u16 Ks[2][64 * 72];
  __shared__ u16 Vs[2][64 * 72];
  __shared__ u32 Os[4][32][33];

  const int tid  = threadIdx.x;
  const int w    = tid >> 6;
  const int lane = tid & 63;
  const int lq   = lane & 31;
  const int hi   = lane >> 5;

  const int bid = blockIdx.x;
  const int wg  = (bid & 7) * 64 + (bid >> 3);   // bijective, 512 % 8 == 0
  const int bh  = wg >> 3, qt = wg & 7;
  const long base = (long)bh * (2048 * 64);

  // Q fragments (B-operand), 2 per wave
  s16x8 qf[2][4];
#pragma unroll
  for (int qi = 0; qi < 2; ++qi) {
    const int qrow = qt * 256 + w * 64 + qi * 32 + lq;
    const u16* qp = qbuf + base + qrow * 64 + 8 * hi;
#pragma unroll
    for (int s = 0; s < 4; ++s) qf[qi][s] = *(const s16x8*)(qp + 16 * s);
  }

  f32x16 oacc[2][2];
  float lacc[2][8];
#pragma unroll
  for (int qi = 0; qi < 2; ++qi) {
#pragma unroll
    for (int r = 0; r < 16; ++r) { oacc[qi][0][r] = 0.f; oacc[qi][1][r] = 0.f; }
#pragma unroll
    for (int r = 0; r < 8; ++r) lacc[qi][r] = 0.f;
  }

  const u16* bslice = biasr + (long)((qt * 4 + w) * 2) * 65536 + lane * 8;

  // staging geometry: row sr in [0,32), chunk scc in [0,8)
  const int sr  = tid >> 3;
  const int scc = tid & 7;
  const u16* kg = kbuf  + base + sr * 64   + scc * 8;   // + kt*4096 ; +2048 = rows 32..63
  const u16* vg = vtbuf + base + sr * 2048 + scc * 8;   // + kt*64   ; +65536 = d 32..63
  const int wo0 = sr * 72 + scc * 8;
  const int wo1 = (32 + sr) * 72 + scc * 8;

  u32x4 bbA[2][4], bbB[2][4];

#define LOADB(BB, KT)                                                          \
  {                                                                            \
    _Pragma("unroll")                                                          \
    for (int qi = 0; qi < 2; ++qi)                                             \
      _Pragma("unroll")                                                        \
      for (int k = 0; k < 4; ++k)                                              \
        BB[qi][k] = *(const u32x4*)(bslice + (long)qi * 65536 + (KT) * 2048 + k * 512); \
  }

#define COMPUTE(BUF, BB)                                                       \
  {                                                                            \
    s16x8 kf0[4], kf1[4], vf0[4], vf1[4];                                      \
    {                                                                          \
      const u16* kb0 = &Ks[BUF][lq * 72];                                      \
      const u16* kb1 = &Ks[BUF][(32 + lq) * 72];                               \
      const u16* vb0 = &Vs[BUF][lq * 72];                                      \
      const u16* vb1 = &Vs[BUF][(32 + lq) * 72];                               \
      _Pragma("unroll")                                                        \
      for (int s = 0; s < 4; ++s) {                                            \
        const int off = (2 * s + hi) * 8;                                      \
        kf0[s] = *(const s16x8*)(kb0 + off);                                   \
        kf1[s] = *(const s16x8*)(kb1 + off);                                   \
        vf0[s] = *(const s16x8*)(vb0 + off);                                   \
        vf1[s] = *(const s16x8*)(vb1 + off);                                   \
      }                                                                        \
    }                                                                          \
    _Pragma("unroll")                                                          \
    for (int qi = 0; qi < 2; ++qi) {                                           \
      f32x16 sa0, sa1;                                                         \
      _Pragma("unroll")                                                        \
      for (int jw = 0; jw < 8; ++jw) {                                         \
        const u32 w0 = BB[qi][jw >> 2][jw & 3];                                \
        const u32 w1 = BB[qi][2 + (jw >> 2)][jw & 3];                          \
        sa0[2 * jw]     = __builtin_bit_cast(float, w0 << 16);                 \
        sa0[2 * jw + 1] = __builtin_bit_cast(float, w0 & 0xFFFF0000u);         \
        sa1[2 * jw]     = __builtin_bit_cast(float, w1 << 16);                 \
        sa1[2 * jw + 1] = __builtin_bit_cast(float, w1 & 0xFFFF0000u);         \
      }                                                                        \
      _Pragma("unroll")                                                        \
      for (int s = 0; s < 4; ++s) sa0 = mfma32(kf0[s], qf[qi][s], sa0);        \
      _Pragma("unroll")                                                        \
      for (int s = 0; s < 4; ++s) sa1 = mfma32(kf1[s], qf[qi][s], sa1);        \
      _Pragma("unroll")                                                        \
      for (int r = 0; r < 16; ++r) {                                           \
        sa0[r] = exp2_hw(sa0[r]);                                              \
        sa1[r] = exp2_hw(sa1[r]);                                              \
      }                                                                        \
      _Pragma("unroll")                                                        \
      for (int r = 0; r < 8; ++r)                                              \
        lacc[qi][r] += (sa0[r] + sa0[r + 8]) + (sa1[r] + sa1[r + 8]);          \
      s16x8 pf[4];                                                             \
      _Pragma("unroll")                                                        \
      for (int ks = 0; ks < 4; ++ks) {                                         \
        const f32x16 ps = (ks & 2) ? sa1 : sa0;                                \
        const int o = (ks & 1) * 8;                                            \
        u32x4 tt;                                                              \
        tt[0] = cvtpk(ps[o + 0], ps[o + 1]);                                   \
        tt[1] = cvtpk(ps[o + 2], ps[o + 3]);                                   \
        tt[2] = cvtpk(ps[o + 4], ps[o + 5]);                                   \
        tt[3] = cvtpk(ps[o + 6], ps[o + 7]);                                   \
        pf[ks] = __builtin_bit_cast(s16x8, tt);                                \
      }                                                                        \
      _Pragma("unroll")                                                        \
      for (int ks = 0; ks < 4; ++ks) {                                         \
        oacc[qi][0] = mfma32(vf0[ks], pf[ks], oacc[qi][0]);                    \
        oacc[qi][1] = mfma32(vf1[ks], pf[ks], oacc[qi][1]);                    \
      }                                                                        \
    }                                                                          \
  }

  // prologue: stage tile 0, load bias(0)
  {
    const s16x8 a0 = *(const s16x8*)(kg);
    const s16x8 a1 = *(const s16x8*)(kg + 2048);
    const s16x8 b0 = *(const s16x8*)(vg);
    const s16x8 b1 = *(const s16x8*)(vg + 65536);
    *(s16x8*)(&Ks[0][wo0]) = a0;  *(s16x8*)(&Ks[0][wo1]) = a1;
    *(s16x8*)(&Vs[0][wo0]) = b0;  *(s16x8*)(&Vs[0][wo1]) = b1;
  }
  LOADB(bbA, 0);
  __syncthreads();

  for (int kt = 0; kt < 32; kt += 2) {
    // ---- even iter: read buf0, write buf1 (tile kt+1) ----
    s16x8 nk0, nk1, nv0, nv1;
    {
      const u16* kn = kg + (kt + 1) * 4096;
      const u16* vn = vg + (kt + 1) * 64;
      nk0 = *(const s16x8*)(kn);
      nk1 = *(const s16x8*)(kn + 2048);
      nv0 = *(const s16x8*)(vn);
      nv1 = *(const s16x8*)(vn + 65536);
    }
    LOADB(bbB, kt + 1);
    COMPUTE(0, bbA);
    *(s16x8*)(&Ks[1][wo0]) = nk0;
    *(s16x8*)(&Ks[1][wo1]) = nk1;
    *(s16x8*)(&Vs[1][wo0]) = nv0;
    *(s16x8*)(&Vs[1][wo1]) = nv1;
    __syncthreads();

    // ---- odd iter: read buf1, write buf0 (tile kt+2) ----
    if (kt < 30) {
      const u16* kn = kg + (kt + 2) * 4096;
      const u16* vn = vg + (kt + 2) * 64;
      nk0 = *(const s16x8*)(kn);
      nk1 = *(const s16x8*)(kn + 2048);
      nv0 = *(const s16x8*)(vn);
      nv1 = *(const s16x8*)(vn + 65536);
      LOADB(bbA, kt + 2);
    }
    COMPUTE(1, bbB);
    if (kt < 30) {
      *(s16x8*)(&Ks[0][wo0]) = nk0;
      *(s16x8*)(&Ks[0][wo1]) = nk1;
      *(s16x8*)(&Vs[0][wo0]) = nv0;
      *(s16x8*)(&Vs[0][wo1]) = nv1;
    }
    __syncthreads();
  }
#undef LOADB
#undef COMPUTE

  // epilogue: reduce l, normalize, transpose via LDS, store [B, L, H*D] bf16
  const int b = bh >> 4, h = bh & 15;
#pragma unroll
  for (int qi = 0; qi < 2; ++qi) {
    float l = ((lacc[qi][0] + lacc[qi][1]) + (lacc[qi][2] + lacc[qi][3]))
            + ((lacc[qi][4] + lacc[qi][5]) + (lacc[qi][6] + lacc[qi][7]));
    l += __shfl_xor(l, 32, 64);
    const float inv = 1.f / l;
#pragma unroll
    for (int i = 0; i < 8; ++i) {
      const int idx = (i & 1) + 2 * hi + 4 * (i >> 1);   // d0 = 2*idx
      Os[w][lq][idx]      = cvtpk(oacc[qi][0][2 * i] * inv, oacc[qi][0][2 * i + 1] * inv);
      Os[w][lq][idx + 16] = cvtpk(oacc[qi][1][2 * i] * inv, oacc[qi][1][2 * i + 1] * inv);
    }
    __syncthreads();
#pragma unroll
    for (int it = 0; it < 4; ++it) {
      const int q = it * 8 + (lane >> 3);
      const int c = (lane & 7) * 4;
      u32x4 v;
#pragma unroll
      for (int j = 0; j < 4; ++j) v[j] = Os[w][q][c + j];
      const long row = (long)(b * 2048 + qt * 256 + w * 64 + qi * 32 + q);
      *(u32x4*)(oup + row * 1024 + h * 64 + (lane & 7) * 8) = v;
    }
    __syncthreads();
  }
}

extern "C" void kernel_launch(void* const* d_in, const int* in_sizes, int n_in,
                              void* d_out, int out_size, void* d_ws, size_t ws_size,
                              hipStream_t stream) {
  const float* x     = (const float*)d_in[0];
  const float* ab    = (const float*)d_in[1];
  const float* wqkv  = (const float*)d_in[2];
  const float* qbias = (const float*)d_in[3];
  const float* vbias = (const float*)d_in[4];
  const float* wproj = (const float*)d_in[5];
  const float* bproj = (const float*)d_in[6];
  float* out = (float*)d_out;

  // workspace layout (80 MB total)
  char* ws = (char*)d_ws;
  if (ws_size < 83886080u) return;  // refuse to corrupt memory
  u16* xb     = (u16*)(ws);              // 16 MB; reused as oup after QKV GEMM
  u16* wqkvb  = (u16*)(ws + 16777216);   // 6 MB
  u16* wprojb = (u16*)(ws + 23068672);   // 2 MB
  u16* biasr  = (u16*)(ws + 25165824);   // 8 MB  (attn_bias, fragment order)
  u16* qbuf   = (u16*)(ws + 33554432);   // 16 MB  [B,H,L,D] (q pre-scaled)
  u16* kbuf   = (u16*)(ws + 50331648);   // 16 MB  [B,H,L,D]
  u16* vtbuf  = (u16*)(ws + 67108864);   // 16 MB  [B,H,D,L'] (key-permuted)

  cvt<<<dim3(2048), dim3(256), 0, stream>>>(x, xb, 8388608 / 4);
  cvt<<<dim3(512),  dim3(256), 0, stream>>>(wqkv, wqkvb, 3145728 / 4);
  cvt<<<dim3(256),  dim3(256), 0, stream>>>(wproj, wprojb, 1048576 / 4);
  bias_rearrange<<<dim3(2048), dim3(256), 0, stream>>>(ab, biasr);

  gemm_bt<0><<<dim3(24, 64), dim3(256), 0, stream>>>(
      xb, wqkvb, 8192, 3072, 1024, qbias, vbias, qbuf, kbuf, vtbuf, nullptr);

  flash_attn<<<dim3(512), dim3(256), 0, stream>>>(qbuf, kbuf, vtbuf, biasr, xb);

  gemm_bt<1><<<dim3(8, 64), dim3(256), 0, stream>>>(
      xb, wprojb, 8192, 1024, 1024, bproj, nullptr, nullptr, nullptr, nullptr, out);
}

// Round 15
// 234.694 us; speedup vs baseline: 1.6114x; 1.0615x over previous
//
#include <hip/hip_runtime.h>
#include <hip/hip_bf16.h>

typedef unsigned short u16;
typedef unsigned int   u32;

using f32x4  = __attribute__((ext_vector_type(4)))  float;
using f32x16 = __attribute__((ext_vector_type(16))) float;
using s16x8  = __attribute__((ext_vector_type(8)))  short;
using b16x8  = __attribute__((ext_vector_type(8)))  __bf16;
using u32x4  = __attribute__((ext_vector_type(4)))  u32;

#define LOG2E 1.44269504088896f
#define QSC   (0.03125f * LOG2E)   // SCALE * log2(e), folded into q

__device__ __forceinline__ f32x4 mfma16(s16x8 a, s16x8 b, f32x4 c) {
  return __builtin_amdgcn_mfma_f32_16x16x32_bf16(
      __builtin_bit_cast(b16x8, a), __builtin_bit_cast(b16x8, b), c, 0, 0, 0);
}
__device__ __forceinline__ f32x16 mfma32(s16x8 a, s16x8 b, f32x16 c) {
  return __builtin_amdgcn_mfma_f32_32x32x16_bf16(
      __builtin_bit_cast(b16x8, a), __builtin_bit_cast(b16x8, b), c, 0, 0, 0);
}

__device__ __forceinline__ u16 f2bf(float f) {
  u32 u = __builtin_bit_cast(u32, f);
  u = (u + 0x7FFFu + ((u >> 16) & 1u)) >> 16;
  return (u16)u;
}
__device__ __forceinline__ float exp2_hw(float x) {
  float r;
  asm("v_exp_f32 %0, %1" : "=v"(r) : "v"(x));
  return r;
}
__device__ __forceinline__ u32 cvtpk(float a, float b) {   // (lo=a, hi=b) bf16 pair, RNE
  u32 r;
  asm("v_cvt_pk_bf16_f32 %0, %1, %2" : "=v"(r) : "v"(a), "v"(b));
  return r;
}

// async global->LDS, 16B per lane; LDS dest = wave-uniform base + lane*16
__device__ __forceinline__ void gload16(const void* g, void* l) {
  __builtin_amdgcn_global_load_lds(
      (const __attribute__((address_space(1))) u32*)g,
      (__attribute__((address_space(3))) u32*)l, 16, 0, 0);
}

// ---------------- fp32 -> bf16 convert ----------------
__global__ void cvt(const float* __restrict__ in, u16* __restrict__ out, int n4) {
  int i = blockIdx.x * blockDim.x + threadIdx.x;
  int stride = gridDim.x * blockDim.x;
  for (; i < n4; i += stride) {
    float4 v = ((const float4*)in)[i];
    ushort4 o;
    o.x = f2bf(v.x); o.y = f2bf(v.y); o.z = f2bf(v.z); o.w = f2bf(v.w);
    ((ushort4*)out)[i] = o;
  }
}

// ---------------- bias rearrange into flash fragment order ----------------
// layout: flat slot s = q>>5 (64 slots of 32 queries),
// then [kt(32)][chunk(4)][lane(64)][8 vals] bf16, *LOG2E.
// vidx = chunk*8+e ; kb=vidx>>4, r=vidx&15
// true key = kt*64 + kb*32 + (r&3) + 8*(r>>2) + 4*(lane>>5)
__global__ void bias_rearrange(const float* __restrict__ ab, u16* __restrict__ out) {
  const int idx  = blockIdx.x * 256 + threadIdx.x;   // 0..524287
  const int lane = idx & 63;
  const int vo   = ((idx >> 6) & 3) * 8;             // vidx base: 0,8,16,24
  const int kt   = (idx >> 8) & 31;
  const int slot = idx >> 13;                        // 0..63 (= q>>5)
  const int hi   = lane >> 5;
  const int q    = slot * 32 + (lane & 31);
  const int kb   = vo >> 4;                 // 0 or 1
  const int so   = (vo & 8) << 1;           // +16 for r=8..15 octet
  const int kbase = kt * 64 + kb * 32 + so + 4 * hi;
  const float* src = ab + (long)q * 2048 + kbase;
  const float4 a = *(const float4*)(src);        // keys +0..3
  const float4 b = *(const float4*)(src + 8);    // keys +8..11
  u16 o[8];
  o[0] = f2bf(a.x * LOG2E); o[1] = f2bf(a.y * LOG2E);
  o[2] = f2bf(a.z * LOG2E); o[3] = f2bf(a.w * LOG2E);
  o[4] = f2bf(b.x * LOG2E); o[5] = f2bf(b.y * LOG2E);
  o[6] = f2bf(b.z * LOG2E); o[7] = f2bf(b.w * LOG2E);
  *(s16x8*)(out + (long)idx * 8) = *(s16x8*)o;
}

// ---------------- GEMM: C[M,N] = A[M,K] @ B[N,K]^T  (both bf16, row-major) ----
// 2-phase double-buffered staging (T3 minimum): stage(next) overlaps
// compute(cur); one vmcnt(0)+barrier per K-tile.
template<int EPI>
__global__ __launch_bounds__(256)
void gemm_bt(const u16* __restrict__ A, const u16* __restrict__ Bm,
             int M, int N, int K,
             const float* __restrict__ bias0, const float* __restrict__ bias1,
             u16* __restrict__ oq, u16* __restrict__ ok, u16* __restrict__ ov,
             float* __restrict__ outf)
{
  __shared__ u16 As[2][128 * 32];
  __shared__ u16 Bs[2][128 * 32];

  const int tid  = threadIdx.x;
  const int w    = tid >> 6;
  const int lane = tid & 63;
  const int lr   = lane & 15;
  const int lg   = lane >> 4;
  const int wr   = w >> 1, wc = w & 1;

  const int bm = blockIdx.y, bn = blockIdx.x;

  f32x4 acc[4][4];
#pragma unroll
  for (int i = 0; i < 4; ++i)
#pragma unroll
    for (int j = 0; j < 4; ++j) acc[i][j] = (f32x4){0.f, 0.f, 0.f, 0.f};

  const int rowA = bm * 128 + (tid >> 2);
  const int rowB = bn * 128 + (tid >> 2);
  const int colk = (tid & 3) * 8;

  const u16* ga0 = A  + (long)rowA * K + colk;
  const u16* gb0 = Bm + (long)rowB * K + colk;

  // prologue: stage tile 0
  gload16(ga0,          &As[0][w * 512]);
  gload16(ga0 + 64 * K, &As[0][2048 + w * 512]);
  gload16(gb0,          &Bs[0][w * 512]);
  gload16(gb0 + 64 * K, &Bs[0][2048 + w * 512]);
  asm volatile("s_waitcnt vmcnt(0)" ::: "memory");
  __syncthreads();

  const int NT = K >> 5;
  for (int t = 0; t < NT; ++t) {
    const int cur = t & 1;
    if (t + 1 < NT) {            // stage next tile into the other buffer
      const u16* ga = ga0 + (t + 1) * 32;
      const u16* gb = gb0 + (t + 1) * 32;
      gload16(ga,          &As[cur ^ 1][w * 512]);
      gload16(ga + 64 * K, &As[cur ^ 1][2048 + w * 512]);
      gload16(gb,          &Bs[cur ^ 1][w * 512]);
      gload16(gb + 64 * K, &Bs[cur ^ 1][2048 + w * 512]);
    }

    s16x8 af[4], bfr[4];
#pragma unroll
    for (int mi = 0; mi < 4; ++mi)
      af[mi] = *(const s16x8*)(&As[cur][(wr * 64 + mi * 16 + lr) * 32 + lg * 8]);
#pragma unroll
    for (int ni = 0; ni < 4; ++ni)
      bfr[ni] = *(const s16x8*)(&Bs[cur][(wc * 64 + ni * 16 + lr) * 32 + lg * 8]);
#pragma unroll
    for (int mi = 0; mi < 4; ++mi)
#pragma unroll
      for (int ni = 0; ni < 4; ++ni)
        acc[mi][ni] = mfma16(af[mi], bfr[ni], acc[mi][ni]);

    asm volatile("s_waitcnt vmcnt(0)" ::: "memory");   // next tile landed
    __syncthreads();                                    // all reads of cur done
  }

  const int gm0 = bm * 128 + wr * 64;
  const int gn0 = bn * 128 + wc * 64;

#pragma unroll
  for (int mi = 0; mi < 4; ++mi) {
#pragma unroll
    for (int ni = 0; ni < 4; ++ni) {
      const int col  = gn0 + ni * 16 + lr;
      const int row0 = gm0 + mi * 16 + lg * 4;
      if (EPI == 0) {
        const int which = col >> 10;          // 0=q 1=k 2=v
        const int cj    = col & 1023;
        const float badd = (which == 0) ? bias0[cj] : (which == 2 ? bias1[cj] : 0.f);
        const int h = cj >> 6, d = cj & 63;
#pragma unroll
        for (int r = 0; r < 4; ++r) {
          const int rowg = row0 + r;           // = b*2048 + l
          const int b = rowg >> 11, l = rowg & 2047;
          const int bh = b * 16 + h;
          float val = acc[mi][ni][r] + badd;
          if (which == 0) val *= QSC;          // fold softmax scale+log2e into q
          const u16 o = f2bf(val);
          if (which == 0)      oq[(bh * 2048 + l) * 64 + d] = o;
          else if (which == 1) ok[(bh * 2048 + l) * 64 + d] = o;
          else {
            // permute key bits 2<->3 so flash PV B-frags are lane-local
            const int lp = (l & ~12) | ((l & 4) << 1) | ((l & 8) >> 1);
            ov[(bh * 64 + d) * 2048 + lp] = o;
          }
        }
      } else {
        const float badd = bias0[col];
#pragma unroll
        for (int r = 0; r < 4; ++r)
          outf[(long)(row0 + r) * N + col] = acc[mi][ni][r] + badd;
      }
    }
  }
}

// ---------------- flash attention ----------------
// TLP build: 1024 blocks -> (bh 0..63, qt2 0..15), XCD-swizzled (8 bh/XCD).
// 256 threads = 4 waves; wave owns ONE 32-query fragment (r11's proven qi=1
// numerics) + r13's proven coalesced reg-staged LDS K/V tiles (padded rows).
// Os is ALIASED onto Ks (dead after final loop barrier) -> LDS 36.9KB ->
// 3 blocks/CU; qi=1 drops VGPR to ~160 -> 3 waves/SIMD. 12 waves/CU (+50%).
// Fixed-max softmax (P = 2^s), lane-local cvt_pk P-frags, key-permuted V.
// NOTE: plain __launch_bounds__(256) — min-waves arg condemned (r8/r9/r11).
__global__ __launch_bounds__(256)
void flash_attn(const u16* __restrict__ qbuf, const u16* __restrict__ kbuf,
                const u16* __restrict__ vtbuf, const u16* __restrict__ biasr,
                u16* __restrict__ oup)
{
  __shared__ u16 Ks[2][64 * 72];
  __shared__ u16 Vs[2][64 * 72];

  const int tid  = threadIdx.x;
  const int w    = tid >> 6;
  const int lane = tid & 63;
  const int lq   = lane & 31;
  const int hi   = lane >> 5;

  const int bid = blockIdx.x;
  const int swz = (bid & 7) * 128 + (bid >> 3);   // bijective, 1024 % 8 == 0
  const int bh  = swz >> 4, qt2 = swz & 15;
  const long base = (long)bh * (2048 * 64);

  // Q fragment (B-operand), one per wave
  const int qrow = qt2 * 128 + w * 32 + lq;
  s16x8 qf[4];
  {
    const u16* qp = qbuf + base + qrow * 64 + 8 * hi;
#pragma unroll
    for (int s = 0; s < 4; ++s) qf[s] = *(const s16x8*)(qp + 16 * s);
  }

  f32x16 oacc0, oacc1;
  float lacc[8];
#pragma unroll
  for (int r = 0; r < 16; ++r) { oacc0[r] = 0.f; oacc1[r] = 0.f; }
#pragma unroll
  for (int r = 0; r < 8; ++r) lacc[r] = 0.f;

  // bias slot = qrow>>5 = qt2*4 + w
  const u16* bslice = biasr + (long)(qt2 * 4 + w) * 65536 + lane * 8;

  // staging geometry: row sr in [0,32), chunk scc in [0,8)
  const int sr  = tid >> 3;
  const int scc = tid & 7;
  const u16* kg = kbuf  + base + sr * 64   + scc * 8;   // + kt*4096 ; +2048 = rows 32..63
  const u16* vg = vtbuf + base + sr * 2048 + scc * 8;   // + kt*64   ; +65536 = d 32..63
  const int wo0 = sr * 72 + scc * 8;
  const int wo1 = (32 + sr) * 72 + scc * 8;

  // prologue: stage tile 0
  {
    const s16x8 a0 = *(const s16x8*)(kg);
    const s16x8 a1 = *(const s16x8*)(kg + 2048);
    const s16x8 b0 = *(const s16x8*)(vg);
    const s16x8 b1 = *(const s16x8*)(vg + 65536);
    *(s16x8*)(&Ks[0][wo0]) = a0;  *(s16x8*)(&Ks[0][wo1]) = a1;
    *(s16x8*)(&Vs[0][wo0]) = b0;  *(s16x8*)(&Vs[0][wo1]) = b1;
  }
  __syncthreads();

  for (int kt = 0; kt < 32; ++kt) {
    const int cur = kt & 1;

    // issue next tile's global loads early (land under this iter's compute)
    s16x8 nk0, nk1, nv0, nv1;
    if (kt < 31) {
      const u16* kn = kg + (kt + 1) * 4096;
      const u16* vn = vg + (kt + 1) * 64;
      nk0 = *(const s16x8*)(kn);
      nk1 = *(const s16x8*)(kn + 2048);
      nv0 = *(const s16x8*)(vn);
      nv1 = *(const s16x8*)(vn + 65536);
    }

    // K/V fragments from LDS (padded rows; bank-balanced)
    s16x8 kf0[4], kf1[4], vf0[4], vf1[4];
    {
      const u16* kb0 = &Ks[cur][lq * 72];
      const u16* kb1 = &Ks[cur][(32 + lq) * 72];
      const u16* vb0 = &Vs[cur][lq * 72];
      const u16* vb1 = &Vs[cur][(32 + lq) * 72];
#pragma unroll
      for (int s = 0; s < 4; ++s) {
        const int off = (2 * s + hi) * 8;
        kf0[s] = *(const s16x8*)(kb0 + off);
        kf1[s] = *(const s16x8*)(kb1 + off);
        vf0[s] = *(const s16x8*)(vb0 + off);
        vf1[s] = *(const s16x8*)(vb1 + off);
      }
    }

    // bias fragments (coalesced dwordx4, bf16 pairs)
    u32x4 bb[4];
#pragma unroll
    for (int k = 0; k < 4; ++k)
      bb[k] = *(const u32x4*)(bslice + kt * 2048 + k * 512);

    // accumulator init from bias (1 VALU op per value)
    f32x16 sa0, sa1;
#pragma unroll
    for (int jw = 0; jw < 8; ++jw) {
      const u32 w0 = bb[jw >> 2][jw & 3];
      const u32 w1 = bb[2 + (jw >> 2)][jw & 3];
      sa0[2 * jw]     = __builtin_bit_cast(float, w0 << 16);
      sa0[2 * jw + 1] = __builtin_bit_cast(float, w0 & 0xFFFF0000u);
      sa1[2 * jw]     = __builtin_bit_cast(float, w1 << 16);
      sa1[2 * jw + 1] = __builtin_bit_cast(float, w1 & 0xFFFF0000u);
    }

    // S^T = K Q^T + bias  (log2 domain; q pre-scaled by QSC)
#pragma unroll
    for (int s = 0; s < 4; ++s) sa0 = mfma32(kf0[s], qf[s], sa0);
#pragma unroll
    for (int s = 0; s < 4; ++s) sa1 = mfma32(kf1[s], qf[s], sa1);

    // P = 2^s, no max subtraction; accumulate l partials
#pragma unroll
    for (int r = 0; r < 16; ++r) {
      sa0[r] = exp2_hw(sa0[r]);
      sa1[r] = exp2_hw(sa1[r]);
    }
#pragma unroll
    for (int r = 0; r < 8; ++r)
      lacc[r] += (sa0[r] + sa0[r + 8]) + (sa1[r] + sa1[r + 8]);

    // P fragments (lane-local by V key-permute)
    s16x8 pf[4];
#pragma unroll
    for (int ks = 0; ks < 4; ++ks) {
      const f32x16 ps = (ks & 2) ? sa1 : sa0;
      const int o = (ks & 1) * 8;
      u32x4 tt;
      tt[0] = cvtpk(ps[o + 0], ps[o + 1]);
      tt[1] = cvtpk(ps[o + 2], ps[o + 3]);
      tt[2] = cvtpk(ps[o + 4], ps[o + 5]);
      tt[3] = cvtpk(ps[o + 6], ps[o + 7]);
      pf[ks] = __builtin_bit_cast(s16x8, tt);
    }

    // O^T += V^T P^T
#pragma unroll
    for (int ks = 0; ks < 4; ++ks) {
      oacc0 = mfma32(vf0[ks], pf[ks], oacc0);
      oacc1 = mfma32(vf1[ks], pf[ks], oacc1);
    }

    // write next tile into the other buffer (its readers wait at the barrier)
    if (kt < 31) {
      *(s16x8*)(&Ks[cur ^ 1][wo0]) = nk0;
      *(s16x8*)(&Ks[cur ^ 1][wo1]) = nk1;
      *(s16x8*)(&Vs[cur ^ 1][wo0]) = nv0;
      *(s16x8*)(&Vs[cur ^ 1][wo1]) = nv1;
    }
    __syncthreads();
  }

  // epilogue: reduce l, normalize, transpose via LDS (aliased onto Ks — dead
  // after the final loop barrier), store [B, L, H*D] bf16
  u32 (*Os)[32][33] = (u32(*)[32][33])&Ks[0][0];
  const int b = bh >> 4, h = bh & 15;
  float l = ((lacc[0] + lacc[1]) + (lacc[2] + lacc[3]))
          + ((lacc[4] + lacc[5]) + (lacc[6] + lacc[7]));
  l += __shfl_xor(l, 32, 64);
  const float inv = 1.f / l;
#pragma unroll
  for (int i = 0; i < 8; ++i) {
    const int idx = (i & 1) + 2 * hi + 4 * (i >> 1);   // d0 = 2*idx
    Os[w][lq][idx]      = cvtpk(oacc0[2 * i] * inv, oacc0[2 * i + 1] * inv);
    Os[w][lq][idx + 16] = cvtpk(oacc1[2 * i] * inv, oacc1[2 * i + 1] * inv);
  }
  __syncthreads();
#pragma unroll
  for (int it = 0; it < 4; ++it) {
    const int q = it * 8 + (lane >> 3);
    const int c = (lane & 7) * 4;
    u32x4 v;
#pragma unroll
    for (int j = 0; j < 4; ++j) v[j] = Os[w][q][c + j];
    const long row = (long)(b * 2048 + qt2 * 128 + w * 32 + q);
    *(u32x4*)(oup + row * 1024 + h * 64 + (lane & 7) * 8) = v;
  }
}

extern "C" void kernel_launch(void* const* d_in, const int* in_sizes, int n_in,
                              void* d_out, int out_size, void* d_ws, size_t ws_size,
                              hipStream_t stream) {
  const float* x     = (const float*)d_in[0];
  const float* ab    = (const float*)d_in[1];
  const float* wqkv  = (const float*)d_in[2];
  const float* qbias = (const float*)d_in[3];
  const float* vbias = (const float*)d_in[4];
  const float* wproj = (const float*)d_in[5];
  const float* bproj = (const float*)d_in[6];
  float* out = (float*)d_out;

  // workspace layout (80 MB total)
  char* ws = (char*)d_ws;
  if (ws_size < 83886080u) return;  // refuse to corrupt memory
  u16* xb     = (u16*)(ws);              // 16 MB; reused as oup after QKV GEMM
  u16* wqkvb  = (u16*)(ws + 16777216);   // 6 MB
  u16* wprojb = (u16*)(ws + 23068672);   // 2 MB
  u16* biasr  = (u16*)(ws + 25165824);   // 8 MB  (attn_bias, fragment order)
  u16* qbuf   = (u16*)(ws + 33554432);   // 16 MB  [B,H,L,D] (q pre-scaled)
  u16* kbuf   = (u16*)(ws + 50331648);   // 16 MB  [B,H,L,D]
  u16* vtbuf  = (u16*)(ws + 67108864);   // 16 MB  [B,H,D,L'] (key-permuted)

  cvt<<<dim3(2048), dim3(256), 0, stream>>>(x, xb, 8388608 / 4);
  cvt<<<dim3(512),  dim3(256), 0, stream>>>(wqkv, wqkvb, 3145728 / 4);
  cvt<<<dim3(256),  dim3(256), 0, stream>>>(wproj, wprojb, 1048576 / 4);
  bias_rearrange<<<dim3(2048), dim3(256), 0, stream>>>(ab, biasr);

  gemm_bt<0><<<dim3(24, 64), dim3(256), 0, stream>>>(
      xb, wqkvb, 8192, 3072, 1024, qbias, vbias, qbuf, kbuf, vtbuf, nullptr);

  flash_attn<<<dim3(1024), dim3(256), 0, stream>>>(qbuf, kbuf, vtbuf, biasr, xb);

  gemm_bt<1><<<dim3(8, 64), dim3(256), 0, stream>>>(
      xb, wprojb, 8192, 1024, 1024, bproj, nullptr, nullptr, nullptr, nullptr, out);
}